// Round 16
// baseline (464.274 us; speedup 1.0000x reference)
//
#include <hip/hip_runtime.h>
#include <hip/hip_bf16.h>
#include <stdint.h>

#define NN 100000
#define EE 1600000
#define NBK 391        // fill blocks, 4096 edges each
#define CHUNK 4096
#define NCB 98         // coarse buckets of 1024 nodes (98*1024 >= NN)
#define NPROJ 1563     // (NN+63)/64 proj blocks
#define NS 32          // mred stage-1 splits

// fma of scalar xi with float4 vv into acc[base..base+3]
// (param name must NOT be 'x'/'y'/'z'/'w' — member tokens get macro-substituted!)
#define FMA4(xi, vv, a, base)                      \
  a[(base)+0] = fmaf((xi), (vv).x, a[(base)+0]);   \
  a[(base)+1] = fmaf((xi), (vv).y, a[(base)+1]);   \
  a[(base)+2] = fmaf((xi), (vv).z, a[(base)+2]);   \
  a[(base)+3] = fmaf((xi), (vv).w, a[(base)+3]);

__device__ inline unsigned pack_bf2(float a, float b) {
  __hip_bfloat162 t;
  t.x = __float2bfloat16(a);
  t.y = __float2bfloat16(b);
  return *reinterpret_cast<unsigned*>(&t);
}

// ---------------- per-block LDS histogram over 98 coarse buckets ----------------
__launch_bounds__(256)
__global__ void k_hist(const int* __restrict__ ei, int* __restrict__ histmat) {
  __shared__ int hist[NCB];
  int t = threadIdx.x;
  if (t < NCB) hist[t] = 0;
  __syncthreads();
  int base = blockIdx.x * CHUNK;
  int nb = EE - base; if (nb > CHUNK) nb = CHUNK;
  for (int k = t; k < nb; k += 256)
    atomicAdd(&hist[ei[EE + base + k] >> 10], 1);
  __syncthreads();
  if (t < NCB) histmat[blockIdx.x * NCB + t] = hist[t];
}

// ---------------- scan stage 1: column sums (98 blocks) ----------------
__launch_bounds__(256)
__global__ void k_sumcb(const int* __restrict__ histmat, int* __restrict__ cbsum) {
  __shared__ int red[4];
  int cb = blockIdx.x, t = threadIdx.x;
  int s = 0;
  for (int blk = t; blk < NBK; blk += 256) s += histmat[blk * NCB + cb];
#pragma unroll
  for (int off = 32; off > 0; off >>= 1) s += __shfl_down(s, off);
  if ((t & 63) == 0) red[t >> 6] = s;
  __syncthreads();
  if (t == 0) cbsum[cb] = red[0] + red[1] + red[2] + red[3];
}

// ---------------- scan stage 2: scan 98 sums -> bucket bases ----------------
__launch_bounds__(128)
__global__ void k_scancb(const int* __restrict__ cbsum, int* __restrict__ bstart,
                         int* __restrict__ offsets) {
  __shared__ int sm[128];
  int t = threadIdx.x;
  int v = (t < NCB) ? cbsum[t] : 0;
  sm[t] = v;
  __syncthreads();
  for (int off = 1; off < 128; off <<= 1) {
    int x = (t >= off) ? sm[t - off] : 0;
    __syncthreads();
    sm[t] += x;
    __syncthreads();
  }
  if (t < NCB) bstart[t] = sm[t] - v;
  if (t == 0) { bstart[NCB] = EE; offsets[NN] = EE; }
}

// ---------------- scan stage 3: per-bucket scan over 391 blocks ----------------
__launch_bounds__(512)
__global__ void k_ppos(const int* __restrict__ histmat, const int* __restrict__ bstart,
                       int* __restrict__ ppos) {
  __shared__ int sm[512];
  int cb = blockIdx.x, t = threadIdx.x;
  int v = (t < NBK) ? histmat[t * NCB + cb] : 0;
  sm[t] = v;
  __syncthreads();
  for (int off = 1; off < 512; off <<= 1) {
    int x = (t >= off) ? sm[t - off] : 0;
    __syncthreads();
    sm[t] += x;
    __syncthreads();
  }
  if (t < NBK) ppos[cb * NBK + t] = bstart[cb] + sm[t] - v;
}

// ---------------- fill pass B: LDS radix-partition + contiguous run copy ----------------
__launch_bounds__(256)
__global__ void k_fill_b(const int* __restrict__ ei, const int* __restrict__ ppos,
                         unsigned* __restrict__ brec) {
  __shared__ int hist[NCB], binstart[NCB], bincur[NCB], pbase[NCB];
  __shared__ unsigned lbuf[CHUNK];
  __shared__ unsigned char cbArr[CHUNK];
  int t = threadIdx.x;
  int base = blockIdx.x * CHUNK;
  int nb = EE - base; if (nb > CHUNK) nb = CHUNK;
  if (t < NCB) { hist[t] = 0; pbase[t] = ppos[t * NBK + blockIdx.x]; }
  __syncthreads();
  unsigned rec[16]; int rcb[16]; int cnt = 0;
  for (int k = t; k < nb; k += 256) {
    int s = ei[base + k], d = ei[EE + base + k];
    rec[cnt] = (unsigned)s | ((unsigned)(d & 1023) << 17);  // s < 2^17, dlocal 10b
    rcb[cnt] = d >> 10;
    atomicAdd(&hist[rcb[cnt]], 1);
    cnt++;
  }
  __syncthreads();
  if (t < NCB) binstart[t] = hist[t];
  __syncthreads();
  for (int off = 1; off < NCB; off <<= 1) {
    int v = (t < NCB && t >= off) ? binstart[t - off] : 0;
    __syncthreads();
    if (t < NCB) binstart[t] += v;
    __syncthreads();
  }
  if (t < NCB) { binstart[t] -= hist[t]; bincur[t] = 0; }
  __syncthreads();
  for (int i = 0; i < cnt; i++) {
    int c = rcb[i];
    int pos = atomicAdd(&bincur[c], 1);
    int p = binstart[c] + pos;
    lbuf[p] = rec[i];
    cbArr[p] = (unsigned char)c;
  }
  __syncthreads();
  for (int i = t; i < nb; i += 256) {
    int c = cbArr[i];
    brec[pbase[c] + (i - binstart[c])] = lbuf[i];
  }
}

// ---------------- fill pass C: bucket-local histogram + scan + place ----------------
__launch_bounds__(1024)
__global__ void k_fill_c(const unsigned* __restrict__ brec, const int* __restrict__ bstart,
                         int* __restrict__ csr, int* __restrict__ offsets,
                         float* __restrict__ dinv) {
  __shared__ int cnt[1024], sm[1024];
  int cbk = blockIdx.x, t = threadIdx.x;
  int nb0 = cbk << 10;
  int nn = NN - nb0; if (nn > 1024) nn = 1024;
  cnt[t] = 0;
  __syncthreads();
  int e0 = bstart[cbk], e1 = bstart[cbk + 1];
  for (int j = e0 + t; j < e1; j += 1024)
    atomicAdd(&cnt[brec[j] >> 17], 1);
  __syncthreads();
  int cv = cnt[t];
  sm[t] = cv;
  __syncthreads();
  for (int off = 1; off < 1024; off <<= 1) {
    int v = (t >= off) ? sm[t - off] : 0;
    __syncthreads();
    sm[t] += v;
    __syncthreads();
  }
  sm[t] -= cv;  // exclusive
  if (t < nn) {
    offsets[nb0 + t] = e0 + sm[t];
    dinv[nb0 + t] = rsqrtf((float)(cv + 1));  // deg includes self loop
  }
  cnt[t] = 0;  // reuse as placement cursor
  __syncthreads();
  for (int j = e0 + t; j < e1; j += 1024) {
    unsigned r = brec[j];
    int dl = r >> 17;
    int p = atomicAdd(&cnt[dl], 1);
    csr[e0 + sm[dl] + p] = r & 0x1FFFF;  // confined to this bucket's window
  }
}

// ---------------- x~ = bf16(x * dinv[row]) ----------------
__global__ void k_prep(const float* __restrict__ x, const float* __restrict__ dinv,
                       unsigned* __restrict__ xbf2) {
  int i = blockIdx.x * 256 + threadIdx.x;  // pair index
  if (i >= NN * 32) return;
  float dv = dinv[i >> 5];
  float2 v = ((const float2*)x)[i];
  xbf2[i] = pack_bf2(v.x * dv, v.y * dv);
}

// ---------------- ax = A_norm @ x (8-lane-group gather), bf16 output ----------------
__launch_bounds__(256)
__global__ void k_agg_x(const unsigned* __restrict__ xbf2, const int* __restrict__ offsets,
                        const int* __restrict__ csr, const float* __restrict__ dinv,
                        unsigned* __restrict__ axb) {
  int gid = blockIdx.x * 256 + threadIdx.x;
  int n = gid >> 6;
  if (n >= NN) return;
  int lane = gid & 63, q = lane & 7, grp = lane >> 3;
  int e0 = offsets[n], e1 = offsets[n + 1];
  float dv = dinv[n];
  float a[8];
#pragma unroll
  for (int i = 0; i < 8; i++) a[i] = 0.f;
  if (grp == 0) {  // self loop, counted once
    uint4 u = ((const uint4*)(xbf2 + (size_t)n * 32))[q];
    unsigned uu[4] = {u.x, u.y, u.z, u.w};
#pragma unroll
    for (int p = 0; p < 4; p++) {
      __hip_bfloat162 v = *reinterpret_cast<__hip_bfloat162*>(&uu[p]);
      a[2 * p] += __bfloat162float(v.x);
      a[2 * p + 1] += __bfloat162float(v.y);
    }
  }
  for (int base = e0; base < e1; base += 8) {
    int j = base + grp;
    if (j < e1) {
      int s = csr[j];
      uint4 u = ((const uint4*)(xbf2 + (size_t)s * 32))[q];
      unsigned uu[4] = {u.x, u.y, u.z, u.w};
#pragma unroll
      for (int p = 0; p < 4; p++) {
        __hip_bfloat162 v = *reinterpret_cast<__hip_bfloat162*>(&uu[p]);
        a[2 * p] += __bfloat162float(v.x);
        a[2 * p + 1] += __bfloat162float(v.y);
      }
    }
  }
#pragma unroll
  for (int i = 0; i < 8; i++) {
    a[i] += __shfl_xor(a[i], 8);
    a[i] += __shfl_xor(a[i], 16);
    a[i] += __shfl_xor(a[i], 32);
  }
  if (lane < 8) {
    uint4 u;
    u.x = pack_bf2(a[0] * dv, a[1] * dv);
    u.y = pack_bf2(a[2] * dv, a[3] * dv);
    u.z = pack_bf2(a[4] * dv, a[5] * dv);
    u.w = pack_bf2(a[6] * dv, a[7] * dv);
    ((uint4*)(axb + (size_t)n * 32))[q] = u;
  }
}

// ---------------- fused weights: Wfk = WK@Wk^T, Wfv = WV@Wv^T, Wfg = WV@gatW ----------------
__global__ void k_fusew(const float* __restrict__ gcnK_W, const float* __restrict__ gcnK_b,
                        const float* __restrict__ gcnV_W, const float* __restrict__ gcnV_b,
                        const float* __restrict__ mha_in_w, const float* __restrict__ mha_in_b,
                        const float* __restrict__ gat_W,
                        float* __restrict__ Wfk, float* __restrict__ Wfv,
                        float* __restrict__ Wfg, float* __restrict__ bf) {
  int blk = blockIdx.x;
  if (blk < 48) {
    int m = blk >> 4;
    int e = (blk & 15) * 256 + threadIdx.x;  // 0..4095
    int i = e >> 6, c = e & 63;
    float s = 0.f;
    if (m == 0) {
      for (int j = 0; j < 64; j++) s = fmaf(gcnK_W[i * 64 + j], mha_in_w[(64 + c) * 64 + j], s);
      Wfk[e] = s;
    } else if (m == 1) {
      for (int j = 0; j < 64; j++) s = fmaf(gcnV_W[i * 64 + j], mha_in_w[(128 + c) * 64 + j], s);
      Wfv[e] = s;
    } else {
      for (int j = 0; j < 64; j++) s = fmaf(gcnV_W[i * 64 + j], gat_W[j * 64 + c], s);
      Wfg[e] = s;
    }
  } else {
    int t = threadIdx.x;
    if (t < 64) {
      float s = mha_in_b[64 + t];
      for (int j = 0; j < 64; j++) s = fmaf(gcnK_b[j], mha_in_w[(64 + t) * 64 + j], s);
      bf[t] = s;
    } else if (t < 128) {
      int c = t - 64;
      float s = mha_in_b[128 + c];
      for (int j = 0; j < 64; j++) s = fmaf(gcnV_b[j], mha_in_w[(128 + c) * 64 + j], s);
      bf[64 + c] = s;
    } else if (t < 192) {
      int c = t - 128;
      float s = 0.f;
      for (int j = 0; j < 64; j++) s = fmaf(gcnV_b[j], gat_W[j * 64 + c], s);
      bf[128 + c] = s;
    }
  }
}

// ---------------- qh = (super_Q @ Wq^T + bq) * scale ----------------
__global__ void k_qh(const float* __restrict__ sQ, const float* __restrict__ in_w,
                     const float* __restrict__ in_b, float* __restrict__ qh) {
  int t = blockIdx.x * 256 + threadIdx.x;
  if (t >= 640) return;
  int l = t >> 6, c = t & 63;
  float acc = 0.f;
  for (int i = 0; i < 64; i++) acc = fmaf(sQ[l * 64 + i], in_w[c * 64 + i], acc);
  qh[t] = (acc + in_b[c]) * 0.35355339059327373f;  // 1/sqrt(8)
}

// ---------------- k_proj: axb -> hGb, s_dst + FUSED MHA partials ----------------
// Round-15: LDS 69.6KB capped occupancy at 2 blocks/CU (VGPR allowed 4) ->
// latency stalls dominated (VALUBusy 37%). Two-phase weight staging shares one
// 32KB LDS buffer: phase 1 = Wfk|Wfv (K/V FMA + attention), phase 2 = Wfg
// (GAT FMA + outputs). LDS ~52KB -> 3 blocks/CU.
__launch_bounds__(256)
__global__ void k_proj(const unsigned* __restrict__ axb, const float* __restrict__ Wfk,
                       const float* __restrict__ Wfv, const float* __restrict__ Wfg,
                       const float* __restrict__ bf, const float* __restrict__ a_dst,
                       const float* __restrict__ qh,
                       unsigned* __restrict__ hGb, float* __restrict__ s_dstv,
                       float* __restrict__ part) {
  __shared__ float sX[64 * 65];  // +1 pad; reused as reduction scratch at the end
  __shared__ float sW[8192];     // phase 1: Wfk | Wfv ; phase 2: Wfg in [0..4096)
  __shared__ float sB[192], sAd[64], sq[640];
  int t = threadIdx.x;
  int base = blockIdx.x * 64;
  for (int i = t; i < 4096; i += 256) { sW[i] = Wfk[i]; sW[4096 + i] = Wfv[i]; }
  if (t < 192) sB[t] = bf[t];
  if (t < 64) sAd[t] = a_dst[t];
  for (int i = t; i < 640; i += 256) sq[i] = qh[i];
  for (int idx = t; idx < 64 * 8; idx += 256) {
    int rl = idx >> 3, c8 = idx & 7;  // 8 bf16 per uint4 chunk
    int row = base + rl;
    uint4 u = (row < NN) ? ((const uint4*)(axb + (size_t)row * 32))[c8]
                         : make_uint4(0u, 0u, 0u, 0u);
    unsigned uu[4] = {u.x, u.y, u.z, u.w};
    float* dst = sX + rl * 65 + c8 * 8;
#pragma unroll
    for (int p = 0; p < 4; p++) {
      __hip_bfloat162 v = *reinterpret_cast<__hip_bfloat162*>(&uu[p]);
      dst[2 * p] = __bfloat162float(v.x);
      dst[2 * p + 1] = __bfloat162float(v.y);
    }
  }
  __syncthreads();
  int cg = t & 7, rg = t >> 3;  // rows 2rg, 2rg+1; cols 8cg..8cg+7 (= head cg)
  int r0 = rg * 2;
  // ---- phase 1: K + V ----
  float aK[16], aV[16];
#pragma unroll
  for (int i = 0; i < 16; i++) { aK[i] = 0.f; aV[i] = 0.f; }
  {
    const float4* Wk4 = (const float4*)sW;
    const float4* Wv4 = (const float4*)(sW + 4096);
#pragma unroll 2
    for (int i = 0; i < 64; i++) {
      float x0 = sX[r0 * 65 + i];
      float x1 = sX[(r0 + 1) * 65 + i];
      float4 wk0 = Wk4[i * 16 + cg * 2], wk1 = Wk4[i * 16 + cg * 2 + 1];
      float4 wv0 = Wv4[i * 16 + cg * 2], wv1 = Wv4[i * 16 + cg * 2 + 1];
      FMA4(x0, wk0, aK, 0); FMA4(x0, wk1, aK, 4);
      FMA4(x1, wk0, aK, 8); FMA4(x1, wk1, aK, 12);
      FMA4(x0, wv0, aV, 0); FMA4(x0, wv1, aV, 4);
      FMA4(x1, wv0, aV, 8); FMA4(x1, wv1, aV, 12);
    }
  }
  float s[10], o[80];
#pragma unroll
  for (int l = 0; l < 10; l++) s[l] = 0.f;
#pragma unroll
  for (int i = 0; i < 80; i++) o[i] = 0.f;
  const float4* sq4 = (const float4*)sq;
#pragma unroll
  for (int r = 0; r < 2; r++) {
    int row = base + r0 + r;
    if (row >= NN) continue;
    int off = r * 8;
    float kv[8], vv[8];
#pragma unroll
    for (int c = 0; c < 8; c++) {
      kv[c] = aK[off + c] + sB[cg * 8 + c];
      vv[c] = aV[off + c] + sB[64 + cg * 8 + c];
    }
#pragma unroll
    for (int l = 0; l < 10; l++) {
      float4 q0 = sq4[l * 16 + cg * 2], q1 = sq4[l * 16 + cg * 2 + 1];
      float z = q0.x * kv[0] + q0.y * kv[1] + q0.z * kv[2] + q0.w * kv[3] +
                q1.x * kv[4] + q1.y * kv[5] + q1.z * kv[6] + q1.w * kv[7];
      float w = __expf(z);
      s[l] += w;
#pragma unroll
      for (int c = 0; c < 8; c++) o[l * 8 + c] = fmaf(w, vv[c], o[l * 8 + c]);
    }
  }
  // ---- phase 2: G (re-stage Wfg over shared buffer) ----
  __syncthreads();
  for (int i = t; i < 4096; i += 256) sW[i] = Wfg[i];
  __syncthreads();
  float aG[16];
#pragma unroll
  for (int i = 0; i < 16; i++) aG[i] = 0.f;
  {
    const float4* Wg4 = (const float4*)sW;
#pragma unroll 2
    for (int i = 0; i < 64; i++) {
      float x0 = sX[r0 * 65 + i];
      float x1 = sX[(r0 + 1) * 65 + i];
      float4 wg0 = Wg4[i * 16 + cg * 2], wg1 = Wg4[i * 16 + cg * 2 + 1];
      FMA4(x0, wg0, aG, 0); FMA4(x0, wg1, aG, 4);
      FMA4(x1, wg0, aG, 8); FMA4(x1, wg1, aG, 12);
    }
  }
#pragma unroll
  for (int r = 0; r < 2; r++) {
    int row = base + r0 + r;
    bool ok = row < NN;
    int off = r * 8;
    float hg[8];
    float sd = 0.f;
#pragma unroll
    for (int c = 0; c < 8; c++) {
      hg[c] = aG[off + c] + sB[128 + cg * 8 + c];
      sd = fmaf(hg[c], sAd[cg * 8 + c], sd);
    }
    sd += __shfl_xor(sd, 1);
    sd += __shfl_xor(sd, 2);
    sd += __shfl_xor(sd, 4);
    if (ok) {
      uint4 u;
      u.x = pack_bf2(hg[0], hg[1]);
      u.y = pack_bf2(hg[2], hg[3]);
      u.z = pack_bf2(hg[4], hg[5]);
      u.w = pack_bf2(hg[6], hg[7]);
      ((uint4*)(hGb + (size_t)row * 32))[cg] = u;
      if (cg == 0) s_dstv[row] = sd;
    }
  }
  // reduce s/o across the 32 same-head threads per wave (lanes stride 8)
#pragma unroll
  for (int l = 0; l < 10; l++) {
    s[l] += __shfl_xor(s[l], 8);
    s[l] += __shfl_xor(s[l], 16);
    s[l] += __shfl_xor(s[l], 32);
  }
#pragma unroll
  for (int i = 0; i < 80; i++) {
    o[i] += __shfl_xor(o[i], 8);
    o[i] += __shfl_xor(o[i], 16);
    o[i] += __shfl_xor(o[i], 32);
  }
  __syncthreads();  // sX reads done everywhere; safe to reuse as scratch
  float* scratch = sX;  // need 4*720 = 2880 floats <= 4160
  int lane = t & 63, wave = t >> 6;
  if (lane < 8) {
#pragma unroll
    for (int l = 0; l < 10; l++) scratch[wave * 720 + lane * 90 + l] = s[l];
#pragma unroll
    for (int i = 0; i < 80; i++) scratch[wave * 720 + lane * 90 + 10 + i] = o[i];
  }
  __syncthreads();
  for (int j = t; j < 720; j += 256) {
    float v = scratch[j] + scratch[720 + j] + scratch[1440 + j] + scratch[2160 + j];
    part[(size_t)blockIdx.x * 720 + j] = v;  // coalesced per block
  }
}

// ---------------- mred stage 1: 32 splits x 720 cols (coalesced) ----------------
__launch_bounds__(256)
__global__ void k_mred1(const float* __restrict__ part, float* __restrict__ part2) {
  int blk = blockIdx.x, t = threadIdx.x;
  int per = (NPROJ + NS - 1) / NS;  // 49
  int b0 = blk * per, b1 = b0 + per; if (b1 > NPROJ) b1 = NPROJ;
  float v0 = 0.f, v1 = 0.f, v2 = 0.f;
  for (int b = b0; b < b1; b++) {
    const float* row = part + (size_t)b * 720;
    v0 += row[t];
    if (t + 256 < 720) v1 += row[t + 256];
    if (t + 512 < 720) v2 += row[t + 512];
  }
  part2[(size_t)blk * 720 + t] = v0;
  if (t + 256 < 720) part2[(size_t)blk * 720 + t + 256] = v1;
  if (t + 512 < 720) part2[(size_t)blk * 720 + t + 512] = v2;
}

// ---------------- mred stage 2: fold 32 splits -> acc (k_context layout) ----------------
__global__ void k_mred2(const float* __restrict__ part2, float* __restrict__ acc) {
  int t = blockIdx.x * 256 + threadIdx.x;
  if (t >= 720) return;
  int cg = t / 90, j = t % 90;
  float v = 0.f;
#pragma unroll
  for (int s = 0; s < NS; s++) v += part2[(size_t)s * 720 + t];
  if (j < 10) acc[cg * 10 + j] = v;
  else acc[80 + cg * 80 + (j - 10)] = v;
}

// ---------------- softmax finalize -> cluster -> context -> a_eff ----------------
__global__ void k_context(const float* __restrict__ acc, const float* __restrict__ out_w,
                          const float* __restrict__ out_b, const float* __restrict__ a_src,
                          const float* __restrict__ gat_Wc, float* __restrict__ aeff) {
  __shared__ float po[640], cl[640], ctx[64];
  int t = threadIdx.x;  // blockDim = 640
  {
    int h = t / 80, r = t % 80, l = r >> 3, j = r & 7;
    po[l * 64 + h * 8 + j] = acc[80 + t] / acc[h * 10 + l];
  }
  __syncthreads();
  {
    int l = t >> 6, d = t & 63;
    float v = out_b[d];
    for (int c = 0; c < 64; c++) v = fmaf(po[l * 64 + c], out_w[d * 64 + c], v);
    cl[t] = v;
  }
  __syncthreads();
  if (t < 64) {
    float m = 0.f;
#pragma unroll
    for (int l = 0; l < 10; l++) m += cl[l * 64 + t];
    ctx[t] = m * 0.1f;
  }
  __syncthreads();
  if (t < 64) {
    float v = a_src[t];
    for (int i = 0; i < 64; i++) v = fmaf(ctx[i], gat_Wc[i * 64 + t], v);
    aeff[t] = v;
  }
}

// ---------------- s_src[n] = dot(hG[n], a_eff) ----------------
__launch_bounds__(256)
__global__ void k_ssrc(const unsigned* __restrict__ hGb, const float* __restrict__ aeff,
                       float* __restrict__ s_src) {
  int gid = blockIdx.x * 256 + threadIdx.x;
  int n = gid >> 6, lane = gid & 63;
  if (n >= NN) return;
  const __hip_bfloat16* hp = (const __hip_bfloat16*)hGb;
  float v = __bfloat162float(hp[(size_t)n * 64 + lane]) * aeff[lane];
#pragma unroll
  for (int off = 32; off > 0; off >>= 1) v += __shfl_xor(v, off);
  if (lane == 0) s_src[n] = v;
}

// ---------------- GAT: 8-lane-group gather ----------------
__launch_bounds__(256)
__global__ void k_gat(const int* __restrict__ offsets, const int* __restrict__ csr,
                      const float* __restrict__ s_src, const float* __restrict__ s_dstv,
                      const unsigned* __restrict__ hGb, const float* __restrict__ gat_b,
                      float* __restrict__ g) {
  int gid = blockIdx.x * 256 + threadIdx.x;
  int n = gid >> 6;
  if (n >= NN) return;
  int lane = gid & 63, q = lane & 7, grp = lane >> 3;
  int e0 = offsets[n], e1 = offsets[n + 1];
  float sd = s_dstv[n];
  float den = 0.f;
  float a[8];
#pragma unroll
  for (int i = 0; i < 8; i++) a[i] = 0.f;
  for (int base = e0; base < e1; base += 8) {
    int j = base + grp;
    if (j < e1) {
      int s = csr[j];
      float z = s_src[s] + sd;
      z = z > 0.f ? z : 0.2f * z;
      float ex = __expf(z);  // logits O(1): softmax shift-invariant, skip segment-max
      den += ex;
      uint4 u = ((const uint4*)(hGb + (size_t)s * 32))[q];
      unsigned uu[4] = {u.x, u.y, u.z, u.w};
#pragma unroll
      for (int p = 0; p < 4; p++) {
        __hip_bfloat162 v = *reinterpret_cast<__hip_bfloat162*>(&uu[p]);
        a[2 * p] = fmaf(ex, __bfloat162float(v.x), a[2 * p]);
        a[2 * p + 1] = fmaf(ex, __bfloat162float(v.y), a[2 * p + 1]);
      }
    }
  }
  den += __shfl_xor(den, 8);
  den += __shfl_xor(den, 16);
  den += __shfl_xor(den, 32);
#pragma unroll
  for (int i = 0; i < 8; i++) {
    a[i] += __shfl_xor(a[i], 8);
    a[i] += __shfl_xor(a[i], 16);
    a[i] += __shfl_xor(a[i], 32);
  }
  float inv = 1.f / (den + 1e-16f);
  if (lane < 8) {
    float4* op = (float4*)(g + (size_t)n * 64 + q * 8);
    op[0] = make_float4(a[0] * inv + gat_b[q * 8 + 0], a[1] * inv + gat_b[q * 8 + 1],
                        a[2] * inv + gat_b[q * 8 + 2], a[3] * inv + gat_b[q * 8 + 3]);
    op[1] = make_float4(a[4] * inv + gat_b[q * 8 + 4], a[5] * inv + gat_b[q * 8 + 5],
                        a[6] * inv + gat_b[q * 8 + 6], a[7] * inv + gat_b[q * 8 + 7]);
  }
}

// ---------------- MLP stage 1: h1 = relu(g@W1+b1) -> bf16 (2r x 8c / thread) ----------------
__launch_bounds__(256)
__global__ void k_mlp1(const float* __restrict__ g, const float* __restrict__ W1,
                       const float* __restrict__ b1, unsigned* __restrict__ h1b) {
  __shared__ float sX[32 * 65];
  __shared__ float sW[64 * 128];
  __shared__ float sb[128];
  int t = threadIdx.x;
  int base = blockIdx.x * 32;
  for (int i = t; i < 8192; i += 256) sW[i] = W1[i];
  if (t < 128) sb[t] = b1[t];
  for (int idx = t; idx < 32 * 16; idx += 256) {
    int rl = idx >> 4, k4 = idx & 15;
    int row = base + rl;
    float4 v = (row < NN) ? ((const float4*)g)[(size_t)row * 16 + k4]
                          : make_float4(0.f, 0.f, 0.f, 0.f);
    sX[rl * 65 + 4 * k4 + 0] = v.x;
    sX[rl * 65 + 4 * k4 + 1] = v.y;
    sX[rl * 65 + 4 * k4 + 2] = v.z;
    sX[rl * 65 + 4 * k4 + 3] = v.w;
  }
  __syncthreads();
  int cg = t & 15, rg = t >> 4;  // rows 2rg, 2rg+1; cols 8cg..8cg+7
  int r0 = rg * 2;
  float a0[8], a1[8];
#pragma unroll
  for (int i = 0; i < 8; i++) { a0[i] = 0.f; a1[i] = 0.f; }
  const float4* W4 = (const float4*)sW;
#pragma unroll 4
  for (int i = 0; i < 64; i++) {
    float x0 = sX[r0 * 65 + i];
    float x1 = sX[(r0 + 1) * 65 + i];
    float4 w0 = W4[i * 32 + cg * 2], w1 = W4[i * 32 + cg * 2 + 1];
    FMA4(x0, w0, a0, 0); FMA4(x0, w1, a0, 4);
    FMA4(x1, w0, a1, 0); FMA4(x1, w1, a1, 4);
  }
#pragma unroll
  for (int r = 0; r < 2; r++) {
    int row = base + r0 + r;
    if (row >= NN) continue;
    float* a = r ? a1 : a0;
    float h[8];
#pragma unroll
    for (int c = 0; c < 8; c++) h[c] = fmaxf(a[c] + sb[cg * 8 + c], 0.f);
    uint4 u;
    u.x = pack_bf2(h[0], h[1]);
    u.y = pack_bf2(h[2], h[3]);
    u.z = pack_bf2(h[4], h[5]);
    u.w = pack_bf2(h[6], h[7]);
    ((uint4*)(h1b + (size_t)row * 64))[cg] = u;
  }
}

// ---------------- MLP stage 2: out = relu(h1@W2+b2) (2r x 8c / thread) ----------------
__launch_bounds__(256)
__global__ void k_mlp2(const unsigned* __restrict__ h1b, const float* __restrict__ W2,
                       const float* __restrict__ b2, float* __restrict__ out) {
  __shared__ unsigned sH[64 * 65];  // bf16 pairs
  __shared__ float sW[128 * 64];
  __shared__ float sb[64];
  int t = threadIdx.x;
  int base = blockIdx.x * 64;
  for (int i = t; i < 8192; i += 256) sW[i] = W2[i];
  if (t < 64) sb[t] = b2[t];
  for (int idx = t; idx < 64 * 16; idx += 256) {
    int rl = idx >> 4, c4 = idx & 15;
    int row = base + rl;
    uint4 v = (row < NN) ? ((const uint4*)h1b)[(size_t)row * 16 + c4]
                         : make_uint4(0u, 0u, 0u, 0u);
    sH[rl * 65 + 4 * c4 + 0] = v.x;
    sH[rl * 65 + 4 * c4 + 1] = v.y;
    sH[rl * 65 + 4 * c4 + 2] = v.z;
    sH[rl * 65 + 4 * c4 + 3] = v.w;
  }
  __syncthreads();
  int cg = t & 7, rg = t >> 3;  // rows 2rg, 2rg+1; cols 8cg..8cg+7
  int r0 = rg * 2;
  float a0[8], a1[8];
#pragma unroll
  for (int i = 0; i < 8; i++) { a0[i] = 0.f; a1[i] = 0.f; }
  const float4* W4 = (const float4*)sW;
#pragma unroll 2
  for (int kp = 0; kp < 64; kp++) {
    unsigned u0 = sH[r0 * 65 + kp];
    unsigned u1 = sH[(r0 + 1) * 65 + kp];
    float x0a = __uint_as_float(u0 << 16), x0b = __uint_as_float(u0 & 0xffff0000u);
    float x1a = __uint_as_float(u1 << 16), x1b = __uint_as_float(u1 & 0xffff0000u);
    int k0 = 2 * kp, k1 = 2 * kp + 1;
    float4 wa0 = W4[k0 * 16 + cg * 2], wa1 = W4[k0 * 16 + cg * 2 + 1];
    float4 wb0 = W4[k1 * 16 + cg * 2], wb1 = W4[k1 * 16 + cg * 2 + 1];
    FMA4(x0a, wa0, a0, 0); FMA4(x0a, wa1, a0, 4);
    FMA4(x0b, wb0, a0, 0); FMA4(x0b, wb1, a0, 4);
    FMA4(x1a, wa0, a1, 0); FMA4(x1a, wa1, a1, 4);
    FMA4(x1b, wb0, a1, 0); FMA4(x1b, wb1, a1, 4);
  }
#pragma unroll
  for (int r = 0; r < 2; r++) {
    int row = base + r0 + r;
    if (row >= NN) continue;
    float* a = r ? a1 : a0;
    float4* op = (float4*)(out + (size_t)row * 64 + cg * 8);
    op[0] = make_float4(fmaxf(a[0] + sb[cg * 8 + 0], 0.f), fmaxf(a[1] + sb[cg * 8 + 1], 0.f),
                        fmaxf(a[2] + sb[cg * 8 + 2], 0.f), fmaxf(a[3] + sb[cg * 8 + 3], 0.f));
    op[1] = make_float4(fmaxf(a[4] + sb[cg * 8 + 4], 0.f), fmaxf(a[5] + sb[cg * 8 + 5], 0.f),
                        fmaxf(a[6] + sb[cg * 8 + 6], 0.f), fmaxf(a[7] + sb[cg * 8 + 7], 0.f));
  }
}

// ---------------- host ----------------
extern "C" void kernel_launch(void* const* d_in, const int* in_sizes, int n_in,
                              void* d_out, int out_size, void* d_ws, size_t ws_size,
                              hipStream_t stream) {
  (void)in_sizes; (void)n_in; (void)out_size; (void)ws_size;
  const float* x        = (const float*)d_in[0];
  const int*   ei       = (const int*)d_in[1];
  const float* gcnK_W   = (const float*)d_in[2];
  const float* gcnK_b   = (const float*)d_in[3];
  const float* gcnV_W   = (const float*)d_in[4];
  const float* gcnV_b   = (const float*)d_in[5];
  const float* super_Q  = (const float*)d_in[6];
  const float* mha_in_w = (const float*)d_in[7];
  const float* mha_in_b = (const float*)d_in[8];
  const float* mha_out_w= (const float*)d_in[9];
  const float* mha_out_b= (const float*)d_in[10];
  const float* gat_W    = (const float*)d_in[11];
  const float* gat_Wc   = (const float*)d_in[12];
  const float* gat_a_src= (const float*)d_in[13];
  const float* gat_a_dst= (const float*)d_in[14];
  const float* gat_b    = (const float*)d_in[15];
  const float* t1_W     = (const float*)d_in[16];
  const float* t1_b     = (const float*)d_in[17];
  const float* t2_W     = (const float*)d_in[18];
  const float* t2_b     = (const float*)d_in[19];

  char* ws = (char*)d_ws;
  size_t cur = 0;
  auto alloc = [&](size_t bytes) -> char* {
    char* p = ws + cur;
    cur = (cur + bytes + 255) & ~(size_t)255;
    return p;
  };
  // no zero-init needed: every buffer is fully written before first read
  int*      histmat = (int*)alloc((size_t)NBK * NCB * 4);
  int*      cbsum   = (int*)alloc((size_t)NCB * 4);
  int*      ppos    = (int*)alloc((size_t)NCB * NBK * 4);  // transposed [cb][blk]
  int*      bstart  = (int*)alloc((size_t)(NCB + 1) * 4);
  int*      offsets = (int*)alloc((size_t)(NN + 1) * 4);
  float*    dinv    = (float*)alloc((size_t)NN * 4);
  int*      csr     = (int*)alloc((size_t)EE * 4);
  unsigned* brec    = (unsigned*)alloc((size_t)EE * 4);
  float*    Wfk     = (float*)alloc(4096 * 4);
  float*    Wfv     = (float*)alloc(4096 * 4);
  float*    Wfg     = (float*)alloc(4096 * 4);
  float*    bfuse   = (float*)alloc(192 * 4);
  float*    qh      = (float*)alloc(640 * 4);
  float*    aeff    = (float*)alloc(64 * 4);
  float*    macc    = (float*)alloc(720 * 4);
  float*    part    = (float*)alloc((size_t)NPROJ * 720 * 4);  // per-proj-block MHA partials
  float*    part2   = (float*)alloc((size_t)NS * 720 * 4);     // stage-1 sums
  float*    s_src   = (float*)alloc((size_t)NN * 4);
  float*    s_dstv  = (float*)alloc((size_t)NN * 4);
  unsigned* xbf     = (unsigned*)alloc((size_t)NN * 128);   // bf16 x*dinv
  unsigned* axb     = (unsigned*)alloc((size_t)NN * 128);   // bf16 A_norm@x
  unsigned* hGb     = (unsigned*)alloc((size_t)NN * 128);   // bf16 GAT features
  unsigned* h1b     = (unsigned*)alloc((size_t)NN * 64 * 4); // bf16 MLP hidden (128/row)
  float*    g       = (float*)d_out;

  k_hist<<<NBK, 256, 0, stream>>>(ei, histmat);
  k_sumcb<<<NCB, 256, 0, stream>>>(histmat, cbsum);
  k_scancb<<<1, 128, 0, stream>>>(cbsum, bstart, offsets);
  k_ppos<<<NCB, 512, 0, stream>>>(histmat, bstart, ppos);
  k_fill_b<<<NBK, 256, 0, stream>>>(ei, ppos, brec);
  k_fill_c<<<NCB, 1024, 0, stream>>>(brec, bstart, csr, offsets, dinv);
  k_prep<<<(NN * 32 + 255) / 256, 256, 0, stream>>>(x, dinv, xbf);
  k_agg_x<<<NN / 4, 256, 0, stream>>>(xbf, offsets, csr, dinv, axb);
  k_fusew<<<49, 256, 0, stream>>>(gcnK_W, gcnK_b, gcnV_W, gcnV_b, mha_in_w, mha_in_b,
                                  gat_W, Wfk, Wfv, Wfg, bfuse);
  k_qh<<<3, 256, 0, stream>>>(super_Q, mha_in_w, mha_in_b, qh);
  k_proj<<<NPROJ, 256, 0, stream>>>(axb, Wfk, Wfv, Wfg, bfuse, gat_a_dst, qh,
                                    hGb, s_dstv, part);
  k_mred1<<<NS, 256, 0, stream>>>(part, part2);
  k_mred2<<<3, 256, 0, stream>>>(part2, macc);
  k_context<<<1, 640, 0, stream>>>(macc, mha_out_w, mha_out_b, gat_a_src, gat_Wc, aeff);
  k_ssrc<<<NN / 4, 256, 0, stream>>>(hGb, aeff, s_src);
  k_gat<<<NN / 4, 256, 0, stream>>>(offsets, csr, s_src, s_dstv, hGb, gat_b, g);
  k_mlp1<<<(NN + 31) / 32, 256, 0, stream>>>(g, t1_W, t1_b, h1b);
  k_mlp2<<<(NN + 63) / 64, 256, 0, stream>>>(h1b, t2_W, t2_b, g);
}

// Round 17
// 448.571 us; speedup vs baseline: 1.0350x; 1.0350x over previous
//
#include <hip/hip_runtime.h>
#include <hip/hip_bf16.h>
#include <stdint.h>

#define NN 100000
#define EE 1600000
#define NBK 391        // fill blocks, 4096 edges each
#define CHUNK 4096
#define NCB 98         // coarse buckets of 1024 nodes (98*1024 >= NN)
#define NPROJ 1563     // (NN+63)/64 proj blocks
#define NS 32          // mred stage-1 splits

// fma of scalar xi with float4 vv into acc[base..base+3]
// (param name must NOT be 'x'/'y'/'z'/'w' — member tokens get macro-substituted!)
#define FMA4(xi, vv, a, base)                      \
  a[(base)+0] = fmaf((xi), (vv).x, a[(base)+0]);   \
  a[(base)+1] = fmaf((xi), (vv).y, a[(base)+1]);   \
  a[(base)+2] = fmaf((xi), (vv).z, a[(base)+2]);   \
  a[(base)+3] = fmaf((xi), (vv).w, a[(base)+3]);

__device__ inline unsigned pack_bf2(float a, float b) {
  __hip_bfloat162 t;
  t.x = __float2bfloat16(a);
  t.y = __float2bfloat16(b);
  return *reinterpret_cast<unsigned*>(&t);
}

// ---------------- per-block LDS histogram over 98 coarse buckets ----------------
__launch_bounds__(256)
__global__ void k_hist(const int* __restrict__ ei, int* __restrict__ histmat) {
  __shared__ int hist[NCB];
  int t = threadIdx.x;
  if (t < NCB) hist[t] = 0;
  __syncthreads();
  int base = blockIdx.x * CHUNK;
  int nb = EE - base; if (nb > CHUNK) nb = CHUNK;
  for (int k = t; k < nb; k += 256)
    atomicAdd(&hist[ei[EE + base + k] >> 10], 1);
  __syncthreads();
  if (t < NCB) histmat[blockIdx.x * NCB + t] = hist[t];
}

// ---------------- scan stage 1: column sums (98 blocks) ----------------
__launch_bounds__(256)
__global__ void k_sumcb(const int* __restrict__ histmat, int* __restrict__ cbsum) {
  __shared__ int red[4];
  int cb = blockIdx.x, t = threadIdx.x;
  int s = 0;
  for (int blk = t; blk < NBK; blk += 256) s += histmat[blk * NCB + cb];
#pragma unroll
  for (int off = 32; off > 0; off >>= 1) s += __shfl_down(s, off);
  if ((t & 63) == 0) red[t >> 6] = s;
  __syncthreads();
  if (t == 0) cbsum[cb] = red[0] + red[1] + red[2] + red[3];
}

// ---------------- scan stage 2: scan 98 sums -> bucket bases ----------------
__launch_bounds__(128)
__global__ void k_scancb(const int* __restrict__ cbsum, int* __restrict__ bstart,
                         int* __restrict__ offsets) {
  __shared__ int sm[128];
  int t = threadIdx.x;
  int v = (t < NCB) ? cbsum[t] : 0;
  sm[t] = v;
  __syncthreads();
  for (int off = 1; off < 128; off <<= 1) {
    int x = (t >= off) ? sm[t - off] : 0;
    __syncthreads();
    sm[t] += x;
    __syncthreads();
  }
  if (t < NCB) bstart[t] = sm[t] - v;
  if (t == 0) { bstart[NCB] = EE; offsets[NN] = EE; }
}

// ---------------- scan stage 3: per-bucket scan over 391 blocks ----------------
__launch_bounds__(512)
__global__ void k_ppos(const int* __restrict__ histmat, const int* __restrict__ bstart,
                       int* __restrict__ ppos) {
  __shared__ int sm[512];
  int cb = blockIdx.x, t = threadIdx.x;
  int v = (t < NBK) ? histmat[t * NCB + cb] : 0;
  sm[t] = v;
  __syncthreads();
  for (int off = 1; off < 512; off <<= 1) {
    int x = (t >= off) ? sm[t - off] : 0;
    __syncthreads();
    sm[t] += x;
    __syncthreads();
  }
  if (t < NBK) ppos[cb * NBK + t] = bstart[cb] + sm[t] - v;
}

// ---------------- fill pass B: LDS radix-partition + contiguous run copy ----------------
__launch_bounds__(256)
__global__ void k_fill_b(const int* __restrict__ ei, const int* __restrict__ ppos,
                         unsigned* __restrict__ brec) {
  __shared__ int hist[NCB], binstart[NCB], bincur[NCB], pbase[NCB];
  __shared__ unsigned lbuf[CHUNK];
  __shared__ unsigned char cbArr[CHUNK];
  int t = threadIdx.x;
  int base = blockIdx.x * CHUNK;
  int nb = EE - base; if (nb > CHUNK) nb = CHUNK;
  if (t < NCB) { hist[t] = 0; pbase[t] = ppos[t * NBK + blockIdx.x]; }
  __syncthreads();
  unsigned rec[16]; int rcb[16]; int cnt = 0;
  for (int k = t; k < nb; k += 256) {
    int s = ei[base + k], d = ei[EE + base + k];
    rec[cnt] = (unsigned)s | ((unsigned)(d & 1023) << 17);  // s < 2^17, dlocal 10b
    rcb[cnt] = d >> 10;
    atomicAdd(&hist[rcb[cnt]], 1);
    cnt++;
  }
  __syncthreads();
  if (t < NCB) binstart[t] = hist[t];
  __syncthreads();
  for (int off = 1; off < NCB; off <<= 1) {
    int v = (t < NCB && t >= off) ? binstart[t - off] : 0;
    __syncthreads();
    if (t < NCB) binstart[t] += v;
    __syncthreads();
  }
  if (t < NCB) { binstart[t] -= hist[t]; bincur[t] = 0; }
  __syncthreads();
  for (int i = 0; i < cnt; i++) {
    int c = rcb[i];
    int pos = atomicAdd(&bincur[c], 1);
    int p = binstart[c] + pos;
    lbuf[p] = rec[i];
    cbArr[p] = (unsigned char)c;
  }
  __syncthreads();
  for (int i = t; i < nb; i += 256) {
    int c = cbArr[i];
    brec[pbase[c] + (i - binstart[c])] = lbuf[i];
  }
}

// ---------------- fill pass C: bucket-local histogram + scan + place ----------------
__launch_bounds__(1024)
__global__ void k_fill_c(const unsigned* __restrict__ brec, const int* __restrict__ bstart,
                         int* __restrict__ csr, int* __restrict__ offsets,
                         float* __restrict__ dinv) {
  __shared__ int cnt[1024], sm[1024];
  int cbk = blockIdx.x, t = threadIdx.x;
  int nb0 = cbk << 10;
  int nn = NN - nb0; if (nn > 1024) nn = 1024;
  cnt[t] = 0;
  __syncthreads();
  int e0 = bstart[cbk], e1 = bstart[cbk + 1];
  for (int j = e0 + t; j < e1; j += 1024)
    atomicAdd(&cnt[brec[j] >> 17], 1);
  __syncthreads();
  int cv = cnt[t];
  sm[t] = cv;
  __syncthreads();
  for (int off = 1; off < 1024; off <<= 1) {
    int v = (t >= off) ? sm[t - off] : 0;
    __syncthreads();
    sm[t] += v;
    __syncthreads();
  }
  sm[t] -= cv;  // exclusive
  if (t < nn) {
    offsets[nb0 + t] = e0 + sm[t];
    dinv[nb0 + t] = rsqrtf((float)(cv + 1));  // deg includes self loop
  }
  cnt[t] = 0;  // reuse as placement cursor
  __syncthreads();
  for (int j = e0 + t; j < e1; j += 1024) {
    unsigned r = brec[j];
    int dl = r >> 17;
    int p = atomicAdd(&cnt[dl], 1);
    csr[e0 + sm[dl] + p] = r & 0x1FFFF;  // confined to this bucket's window
  }
}

// ---------------- x~ = bf16(x * dinv[row]) ----------------
__global__ void k_prep(const float* __restrict__ x, const float* __restrict__ dinv,
                       unsigned* __restrict__ xbf2) {
  int i = blockIdx.x * 256 + threadIdx.x;  // pair index
  if (i >= NN * 32) return;
  float dv = dinv[i >> 5];
  float2 v = ((const float2*)x)[i];
  xbf2[i] = pack_bf2(v.x * dv, v.y * dv);
}

// ---------------- ax = A_norm @ x (8-lane-group gather), bf16 output ----------------
__launch_bounds__(256)
__global__ void k_agg_x(const unsigned* __restrict__ xbf2, const int* __restrict__ offsets,
                        const int* __restrict__ csr, const float* __restrict__ dinv,
                        unsigned* __restrict__ axb) {
  int gid = blockIdx.x * 256 + threadIdx.x;
  int n = gid >> 6;
  if (n >= NN) return;
  int lane = gid & 63, q = lane & 7, grp = lane >> 3;
  int e0 = offsets[n], e1 = offsets[n + 1];
  float dv = dinv[n];
  float a[8];
#pragma unroll
  for (int i = 0; i < 8; i++) a[i] = 0.f;
  if (grp == 0) {  // self loop, counted once
    uint4 u = ((const uint4*)(xbf2 + (size_t)n * 32))[q];
    unsigned uu[4] = {u.x, u.y, u.z, u.w};
#pragma unroll
    for (int p = 0; p < 4; p++) {
      __hip_bfloat162 v = *reinterpret_cast<__hip_bfloat162*>(&uu[p]);
      a[2 * p] += __bfloat162float(v.x);
      a[2 * p + 1] += __bfloat162float(v.y);
    }
  }
  for (int base = e0; base < e1; base += 8) {
    int j = base + grp;
    if (j < e1) {
      int s = csr[j];
      uint4 u = ((const uint4*)(xbf2 + (size_t)s * 32))[q];
      unsigned uu[4] = {u.x, u.y, u.z, u.w};
#pragma unroll
      for (int p = 0; p < 4; p++) {
        __hip_bfloat162 v = *reinterpret_cast<__hip_bfloat162*>(&uu[p]);
        a[2 * p] += __bfloat162float(v.x);
        a[2 * p + 1] += __bfloat162float(v.y);
      }
    }
  }
#pragma unroll
  for (int i = 0; i < 8; i++) {
    a[i] += __shfl_xor(a[i], 8);
    a[i] += __shfl_xor(a[i], 16);
    a[i] += __shfl_xor(a[i], 32);
  }
  if (lane < 8) {
    uint4 u;
    u.x = pack_bf2(a[0] * dv, a[1] * dv);
    u.y = pack_bf2(a[2] * dv, a[3] * dv);
    u.z = pack_bf2(a[4] * dv, a[5] * dv);
    u.w = pack_bf2(a[6] * dv, a[7] * dv);
    ((uint4*)(axb + (size_t)n * 32))[q] = u;
  }
}

// ---------------- fused weights + qh (merged k_qh: blocks 49..51) ----------------
__global__ void k_fusew(const float* __restrict__ gcnK_W, const float* __restrict__ gcnK_b,
                        const float* __restrict__ gcnV_W, const float* __restrict__ gcnV_b,
                        const float* __restrict__ mha_in_w, const float* __restrict__ mha_in_b,
                        const float* __restrict__ gat_W, const float* __restrict__ sQ,
                        float* __restrict__ Wfk, float* __restrict__ Wfv,
                        float* __restrict__ Wfg, float* __restrict__ bf,
                        float* __restrict__ qh) {
  int blk = blockIdx.x;
  if (blk < 48) {
    int m = blk >> 4;
    int e = (blk & 15) * 256 + threadIdx.x;  // 0..4095
    int i = e >> 6, c = e & 63;
    float s = 0.f;
    if (m == 0) {
      for (int j = 0; j < 64; j++) s = fmaf(gcnK_W[i * 64 + j], mha_in_w[(64 + c) * 64 + j], s);
      Wfk[e] = s;
    } else if (m == 1) {
      for (int j = 0; j < 64; j++) s = fmaf(gcnV_W[i * 64 + j], mha_in_w[(128 + c) * 64 + j], s);
      Wfv[e] = s;
    } else {
      for (int j = 0; j < 64; j++) s = fmaf(gcnV_W[i * 64 + j], gat_W[j * 64 + c], s);
      Wfg[e] = s;
    }
  } else if (blk == 48) {
    int t = threadIdx.x;
    if (t < 64) {
      float s = mha_in_b[64 + t];
      for (int j = 0; j < 64; j++) s = fmaf(gcnK_b[j], mha_in_w[(64 + t) * 64 + j], s);
      bf[t] = s;
    } else if (t < 128) {
      int c = t - 64;
      float s = mha_in_b[128 + c];
      for (int j = 0; j < 64; j++) s = fmaf(gcnV_b[j], mha_in_w[(128 + c) * 64 + j], s);
      bf[64 + c] = s;
    } else if (t < 192) {
      int c = t - 128;
      float s = 0.f;
      for (int j = 0; j < 64; j++) s = fmaf(gcnV_b[j], gat_W[j * 64 + c], s);
      bf[128 + c] = s;
    }
  } else {
    int t = (blk - 49) * 256 + threadIdx.x;
    if (t < 640) {
      int l = t >> 6, c = t & 63;
      float acc = 0.f;
      for (int i = 0; i < 64; i++) acc = fmaf(sQ[l * 64 + i], mha_in_w[c * 64 + i], acc);
      qh[t] = (acc + mha_in_b[c]) * 0.35355339059327373f;  // 1/sqrt(8)
    }
  }
}

// ---------------- k_proj: axb -> hGb, s_dst + FUSED MHA partials ----------------
// Round-15 structure (best measured). Rounds 14/16 falsified both weight-bf16
// and two-phase-LDS variants: occupancy pinned ~17% regardless -> latency-
// structural; hot loop stays fp32 single-phase.
__launch_bounds__(256)
__global__ void k_proj(const unsigned* __restrict__ axb, const float* __restrict__ Wfk,
                       const float* __restrict__ Wfv, const float* __restrict__ Wfg,
                       const float* __restrict__ bf, const float* __restrict__ a_dst,
                       const float* __restrict__ qh,
                       unsigned* __restrict__ hGb, float* __restrict__ s_dstv,
                       float* __restrict__ part) {
  __shared__ float sX[64 * 65];  // +1 pad; reused as reduction scratch after FMA loop
  __shared__ float sWk[4096], sWv[4096], sWg[4096];
  __shared__ float sB[192], sAd[64], sq[640];
  int t = threadIdx.x;
  int base = blockIdx.x * 64;
  for (int i = t; i < 4096; i += 256) { sWk[i] = Wfk[i]; sWv[i] = Wfv[i]; sWg[i] = Wfg[i]; }
  if (t < 192) sB[t] = bf[t];
  if (t < 64) sAd[t] = a_dst[t];
  for (int i = t; i < 640; i += 256) sq[i] = qh[i];
  for (int idx = t; idx < 64 * 8; idx += 256) {
    int rl = idx >> 3, c8 = idx & 7;  // 8 bf16 per uint4 chunk
    int row = base + rl;
    uint4 u = (row < NN) ? ((const uint4*)(axb + (size_t)row * 32))[c8]
                         : make_uint4(0u, 0u, 0u, 0u);
    unsigned uu[4] = {u.x, u.y, u.z, u.w};
    float* dst = sX + rl * 65 + c8 * 8;
#pragma unroll
    for (int p = 0; p < 4; p++) {
      __hip_bfloat162 v = *reinterpret_cast<__hip_bfloat162*>(&uu[p]);
      dst[2 * p] = __bfloat162float(v.x);
      dst[2 * p + 1] = __bfloat162float(v.y);
    }
  }
  __syncthreads();
  int cg = t & 7, rg = t >> 3;  // rows 2rg, 2rg+1; cols 8cg..8cg+7 (= head cg)
  int r0 = rg * 2;
  float aK[16], aV[16], aG[16];
#pragma unroll
  for (int i = 0; i < 16; i++) { aK[i] = 0.f; aV[i] = 0.f; aG[i] = 0.f; }
  const float4* Wk4 = (const float4*)sWk;
  const float4* Wv4 = (const float4*)sWv;
  const float4* Wg4 = (const float4*)sWg;
#pragma unroll 2
  for (int i = 0; i < 64; i++) {
    float x0 = sX[r0 * 65 + i];
    float x1 = sX[(r0 + 1) * 65 + i];
    float4 wk0 = Wk4[i * 16 + cg * 2], wk1 = Wk4[i * 16 + cg * 2 + 1];
    float4 wv0 = Wv4[i * 16 + cg * 2], wv1 = Wv4[i * 16 + cg * 2 + 1];
    float4 wg0 = Wg4[i * 16 + cg * 2], wg1 = Wg4[i * 16 + cg * 2 + 1];
    FMA4(x0, wk0, aK, 0); FMA4(x0, wk1, aK, 4);
    FMA4(x1, wk0, aK, 8); FMA4(x1, wk1, aK, 12);
    FMA4(x0, wv0, aV, 0); FMA4(x0, wv1, aV, 4);
    FMA4(x1, wv0, aV, 8); FMA4(x1, wv1, aV, 12);
    FMA4(x0, wg0, aG, 0); FMA4(x0, wg1, aG, 4);
    FMA4(x1, wg0, aG, 8); FMA4(x1, wg1, aG, 12);
  }
  float s[10], o[80];
#pragma unroll
  for (int l = 0; l < 10; l++) s[l] = 0.f;
#pragma unroll
  for (int i = 0; i < 80; i++) o[i] = 0.f;
  const float4* sq4 = (const float4*)sq;
#pragma unroll
  for (int r = 0; r < 2; r++) {
    int row = base + r0 + r;
    bool ok = row < NN;
    int off = r * 8;
    float kv[8], vv[8], hg[8];
    float sd = 0.f;
#pragma unroll
    for (int c = 0; c < 8; c++) {
      kv[c] = aK[off + c] + sB[cg * 8 + c];
      vv[c] = aV[off + c] + sB[64 + cg * 8 + c];
      hg[c] = aG[off + c] + sB[128 + cg * 8 + c];
      sd = fmaf(hg[c], sAd[cg * 8 + c], sd);
    }
    sd += __shfl_xor(sd, 1);
    sd += __shfl_xor(sd, 2);
    sd += __shfl_xor(sd, 4);
    if (ok) {
      // fused MHA accumulation (q slice for head cg from LDS)
#pragma unroll
      for (int l = 0; l < 10; l++) {
        float4 q0 = sq4[l * 16 + cg * 2], q1 = sq4[l * 16 + cg * 2 + 1];
        float z = q0.x * kv[0] + q0.y * kv[1] + q0.z * kv[2] + q0.w * kv[3] +
                  q1.x * kv[4] + q1.y * kv[5] + q1.z * kv[6] + q1.w * kv[7];
        float w = __expf(z);
        s[l] += w;
#pragma unroll
        for (int c = 0; c < 8; c++) o[l * 8 + c] = fmaf(w, vv[c], o[l * 8 + c]);
      }
      uint4 u;
      u.x = pack_bf2(hg[0], hg[1]);
      u.y = pack_bf2(hg[2], hg[3]);
      u.z = pack_bf2(hg[4], hg[5]);
      u.w = pack_bf2(hg[6], hg[7]);
      ((uint4*)(hGb + (size_t)row * 32))[cg] = u;
      if (cg == 0) s_dstv[row] = sd;
    }
  }
  // reduce s/o across the 32 same-head threads per wave (lanes stride 8)
#pragma unroll
  for (int l = 0; l < 10; l++) {
    s[l] += __shfl_xor(s[l], 8);
    s[l] += __shfl_xor(s[l], 16);
    s[l] += __shfl_xor(s[l], 32);
  }
#pragma unroll
  for (int i = 0; i < 80; i++) {
    o[i] += __shfl_xor(o[i], 8);
    o[i] += __shfl_xor(o[i], 16);
    o[i] += __shfl_xor(o[i], 32);
  }
  __syncthreads();  // sX reads done everywhere; safe to reuse as scratch
  float* scratch = sX;  // need 4*720 = 2880 floats <= 4160
  int lane = t & 63, wave = t >> 6;
  if (lane < 8) {
#pragma unroll
    for (int l = 0; l < 10; l++) scratch[wave * 720 + lane * 90 + l] = s[l];
#pragma unroll
    for (int i = 0; i < 80; i++) scratch[wave * 720 + lane * 90 + 10 + i] = o[i];
  }
  __syncthreads();
  for (int j = t; j < 720; j += 256) {
    float v = scratch[j] + scratch[720 + j] + scratch[1440 + j] + scratch[2160 + j];
    part[(size_t)blockIdx.x * 720 + j] = v;  // coalesced per block
  }
}

// ---------------- mred stage 1: 32 splits x 720 cols (coalesced) ----------------
__launch_bounds__(256)
__global__ void k_mred1(const float* __restrict__ part, float* __restrict__ part2) {
  int blk = blockIdx.x, t = threadIdx.x;
  int per = (NPROJ + NS - 1) / NS;  // 49
  int b0 = blk * per, b1 = b0 + per; if (b1 > NPROJ) b1 = NPROJ;
  float v0 = 0.f, v1 = 0.f, v2 = 0.f;
  for (int b = b0; b < b1; b++) {
    const float* row = part + (size_t)b * 720;
    v0 += row[t];
    if (t + 256 < 720) v1 += row[t + 256];
    if (t + 512 < 720) v2 += row[t + 512];
  }
  part2[(size_t)blk * 720 + t] = v0;
  if (t + 256 < 720) part2[(size_t)blk * 720 + t + 256] = v1;
  if (t + 512 < 720) part2[(size_t)blk * 720 + t + 512] = v2;
}

// ---------------- mred stage 2: fold 32 splits -> acc (k_context layout) ----------------
__global__ void k_mred2(const float* __restrict__ part2, float* __restrict__ acc) {
  int t = blockIdx.x * 256 + threadIdx.x;
  if (t >= 720) return;
  int cg = t / 90, j = t % 90;
  float v = 0.f;
#pragma unroll
  for (int s = 0; s < NS; s++) v += part2[(size_t)s * 720 + t];
  if (j < 10) acc[cg * 10 + j] = v;
  else acc[80 + cg * 80 + (j - 10)] = v;
}

// ---------------- softmax finalize -> cluster -> context -> a_eff ----------------
__global__ void k_context(const float* __restrict__ acc, const float* __restrict__ out_w,
                          const float* __restrict__ out_b, const float* __restrict__ a_src,
                          const float* __restrict__ gat_Wc, float* __restrict__ aeff) {
  __shared__ float po[640], cl[640], ctx[64];
  int t = threadIdx.x;  // blockDim = 640
  {
    int h = t / 80, r = t % 80, l = r >> 3, j = r & 7;
    po[l * 64 + h * 8 + j] = acc[80 + t] / acc[h * 10 + l];
  }
  __syncthreads();
  {
    int l = t >> 6, d = t & 63;
    float v = out_b[d];
    for (int c = 0; c < 64; c++) v = fmaf(po[l * 64 + c], out_w[d * 64 + c], v);
    cl[t] = v;
  }
  __syncthreads();
  if (t < 64) {
    float m = 0.f;
#pragma unroll
    for (int l = 0; l < 10; l++) m += cl[l * 64 + t];
    ctx[t] = m * 0.1f;
  }
  __syncthreads();
  if (t < 64) {
    float v = a_src[t];
    for (int i = 0; i < 64; i++) v = fmaf(ctx[i], gat_Wc[i * 64 + t], v);
    aeff[t] = v;
  }
}

// ---------------- s_src[n] = dot(hG[n], a_eff) ----------------
__launch_bounds__(256)
__global__ void k_ssrc(const unsigned* __restrict__ hGb, const float* __restrict__ aeff,
                       float* __restrict__ s_src) {
  int gid = blockIdx.x * 256 + threadIdx.x;
  int n = gid >> 6, lane = gid & 63;
  if (n >= NN) return;
  const __hip_bfloat16* hp = (const __hip_bfloat16*)hGb;
  float v = __bfloat162float(hp[(size_t)n * 64 + lane]) * aeff[lane];
#pragma unroll
  for (int off = 32; off > 0; off >>= 1) v += __shfl_xor(v, off);
  if (lane == 0) s_src[n] = v;
}

// ---------------- GAT: 8-lane-group gather -> bf16 output ----------------
__launch_bounds__(256)
__global__ void k_gat(const int* __restrict__ offsets, const int* __restrict__ csr,
                      const float* __restrict__ s_src, const float* __restrict__ s_dstv,
                      const unsigned* __restrict__ hGb, const float* __restrict__ gat_b,
                      unsigned* __restrict__ gb) {
  int gid = blockIdx.x * 256 + threadIdx.x;
  int n = gid >> 6;
  if (n >= NN) return;
  int lane = gid & 63, q = lane & 7, grp = lane >> 3;
  int e0 = offsets[n], e1 = offsets[n + 1];
  float sd = s_dstv[n];
  float den = 0.f;
  float a[8];
#pragma unroll
  for (int i = 0; i < 8; i++) a[i] = 0.f;
  for (int base = e0; base < e1; base += 8) {
    int j = base + grp;
    if (j < e1) {
      int s = csr[j];
      float z = s_src[s] + sd;
      z = z > 0.f ? z : 0.2f * z;
      float ex = __expf(z);  // logits O(1): softmax shift-invariant, skip segment-max
      den += ex;
      uint4 u = ((const uint4*)(hGb + (size_t)s * 32))[q];
      unsigned uu[4] = {u.x, u.y, u.z, u.w};
#pragma unroll
      for (int p = 0; p < 4; p++) {
        __hip_bfloat162 v = *reinterpret_cast<__hip_bfloat162*>(&uu[p]);
        a[2 * p] = fmaf(ex, __bfloat162float(v.x), a[2 * p]);
        a[2 * p + 1] = fmaf(ex, __bfloat162float(v.y), a[2 * p + 1]);
      }
    }
  }
  den += __shfl_xor(den, 8);
  den += __shfl_xor(den, 16);
  den += __shfl_xor(den, 32);
#pragma unroll
  for (int i = 0; i < 8; i++) {
    a[i] += __shfl_xor(a[i], 8);
    a[i] += __shfl_xor(a[i], 16);
    a[i] += __shfl_xor(a[i], 32);
  }
  float inv = 1.f / (den + 1e-16f);
  if (lane < 8) {
    // bf16 g intermediate: g consumed only by mlp1 (d_out rewritten by mlp2)
    uint4 u;
    u.x = pack_bf2(a[0] * inv + gat_b[q * 8 + 0], a[1] * inv + gat_b[q * 8 + 1]);
    u.y = pack_bf2(a[2] * inv + gat_b[q * 8 + 2], a[3] * inv + gat_b[q * 8 + 3]);
    u.z = pack_bf2(a[4] * inv + gat_b[q * 8 + 4], a[5] * inv + gat_b[q * 8 + 5]);
    u.w = pack_bf2(a[6] * inv + gat_b[q * 8 + 6], a[7] * inv + gat_b[q * 8 + 7]);
    ((uint4*)(gb + (size_t)n * 32))[q] = u;
  }
}

// ---------------- MLP stage 1: h1 = relu(g@W1+b1) -> bf16 (2r x 8c / thread) ----------------
__launch_bounds__(256)
__global__ void k_mlp1(const unsigned* __restrict__ gb, const float* __restrict__ W1,
                       const float* __restrict__ b1, unsigned* __restrict__ h1b) {
  __shared__ float sX[32 * 65];
  __shared__ float sW[64 * 128];
  __shared__ float sb[128];
  int t = threadIdx.x;
  int base = blockIdx.x * 32;
  for (int i = t; i < 8192; i += 256) sW[i] = W1[i];
  if (t < 128) sb[t] = b1[t];
  for (int idx = t; idx < 32 * 8; idx += 256) {
    int rl = idx >> 3, c8 = idx & 7;
    int row = base + rl;
    uint4 u = (row < NN) ? ((const uint4*)(gb + (size_t)row * 32))[c8]
                         : make_uint4(0u, 0u, 0u, 0u);
    unsigned uu[4] = {u.x, u.y, u.z, u.w};
    float* dst = sX + rl * 65 + c8 * 8;
#pragma unroll
    for (int p = 0; p < 4; p++) {
      __hip_bfloat162 v = *reinterpret_cast<__hip_bfloat162*>(&uu[p]);
      dst[2 * p] = __bfloat162float(v.x);
      dst[2 * p + 1] = __bfloat162float(v.y);
    }
  }
  __syncthreads();
  int cg = t & 15, rg = t >> 4;  // rows 2rg, 2rg+1; cols 8cg..8cg+7
  int r0 = rg * 2;
  float a0[8], a1[8];
#pragma unroll
  for (int i = 0; i < 8; i++) { a0[i] = 0.f; a1[i] = 0.f; }
  const float4* W4 = (const float4*)sW;
#pragma unroll 4
  for (int i = 0; i < 64; i++) {
    float x0 = sX[r0 * 65 + i];
    float x1 = sX[(r0 + 1) * 65 + i];
    float4 w0 = W4[i * 32 + cg * 2], w1 = W4[i * 32 + cg * 2 + 1];
    FMA4(x0, w0, a0, 0); FMA4(x0, w1, a0, 4);
    FMA4(x1, w0, a1, 0); FMA4(x1, w1, a1, 4);
  }
#pragma unroll
  for (int r = 0; r < 2; r++) {
    int row = base + r0 + r;
    if (row >= NN) continue;
    float* a = r ? a1 : a0;
    float h[8];
#pragma unroll
    for (int c = 0; c < 8; c++) h[c] = fmaxf(a[c] + sb[cg * 8 + c], 0.f);
    uint4 u;
    u.x = pack_bf2(h[0], h[1]);
    u.y = pack_bf2(h[2], h[3]);
    u.z = pack_bf2(h[4], h[5]);
    u.w = pack_bf2(h[6], h[7]);
    ((uint4*)(h1b + (size_t)row * 64))[cg] = u;
  }
}

// ---------------- MLP stage 2: out = relu(h1@W2+b2) (2r x 8c / thread) ----------------
__launch_bounds__(256)
__global__ void k_mlp2(const unsigned* __restrict__ h1b, const float* __restrict__ W2,
                       const float* __restrict__ b2, float* __restrict__ out) {
  __shared__ unsigned sH[64 * 65];  // bf16 pairs
  __shared__ float sW[128 * 64];
  __shared__ float sb[64];
  int t = threadIdx.x;
  int base = blockIdx.x * 64;
  for (int i = t; i < 8192; i += 256) sW[i] = W2[i];
  if (t < 64) sb[t] = b2[t];
  for (int idx = t; idx < 64 * 16; idx += 256) {
    int rl = idx >> 4, c4 = idx & 15;
    int row = base + rl;
    uint4 v = (row < NN) ? ((const uint4*)h1b)[(size_t)row * 16 + c4]
                         : make_uint4(0u, 0u, 0u, 0u);
    sH[rl * 65 + 4 * c4 + 0] = v.x;
    sH[rl * 65 + 4 * c4 + 1] = v.y;
    sH[rl * 65 + 4 * c4 + 2] = v.z;
    sH[rl * 65 + 4 * c4 + 3] = v.w;
  }
  __syncthreads();
  int cg = t & 7, rg = t >> 3;  // rows 2rg, 2rg+1; cols 8cg..8cg+7
  int r0 = rg * 2;
  float a0[8], a1[8];
#pragma unroll
  for (int i = 0; i < 8; i++) { a0[i] = 0.f; a1[i] = 0.f; }
  const float4* W4 = (const float4*)sW;
#pragma unroll 2
  for (int kp = 0; kp < 64; kp++) {
    unsigned u0 = sH[r0 * 65 + kp];
    unsigned u1 = sH[(r0 + 1) * 65 + kp];
    float x0a = __uint_as_float(u0 << 16), x0b = __uint_as_float(u0 & 0xffff0000u);
    float x1a = __uint_as_float(u1 << 16), x1b = __uint_as_float(u1 & 0xffff0000u);
    int k0 = 2 * kp, k1 = 2 * kp + 1;
    float4 wa0 = W4[k0 * 16 + cg * 2], wa1 = W4[k0 * 16 + cg * 2 + 1];
    float4 wb0 = W4[k1 * 16 + cg * 2], wb1 = W4[k1 * 16 + cg * 2 + 1];
    FMA4(x0a, wa0, a0, 0); FMA4(x0a, wa1, a0, 4);
    FMA4(x0b, wb0, a0, 0); FMA4(x0b, wb1, a0, 4);
    FMA4(x1a, wa0, a1, 0); FMA4(x1a, wa1, a1, 4);
    FMA4(x1b, wb0, a1, 0); FMA4(x1b, wb1, a1, 4);
  }
#pragma unroll
  for (int r = 0; r < 2; r++) {
    int row = base + r0 + r;
    if (row >= NN) continue;
    float* a = r ? a1 : a0;
    float4* op = (float4*)(out + (size_t)row * 64 + cg * 8);
    op[0] = make_float4(fmaxf(a[0] + sb[cg * 8 + 0], 0.f), fmaxf(a[1] + sb[cg * 8 + 1], 0.f),
                        fmaxf(a[2] + sb[cg * 8 + 2], 0.f), fmaxf(a[3] + sb[cg * 8 + 3], 0.f));
    op[1] = make_float4(fmaxf(a[4] + sb[cg * 8 + 4], 0.f), fmaxf(a[5] + sb[cg * 8 + 5], 0.f),
                        fmaxf(a[6] + sb[cg * 8 + 6], 0.f), fmaxf(a[7] + sb[cg * 8 + 7], 0.f));
  }
}

// ---------------- host ----------------
extern "C" void kernel_launch(void* const* d_in, const int* in_sizes, int n_in,
                              void* d_out, int out_size, void* d_ws, size_t ws_size,
                              hipStream_t stream) {
  (void)in_sizes; (void)n_in; (void)out_size; (void)ws_size;
  const float* x        = (const float*)d_in[0];
  const int*   ei       = (const int*)d_in[1];
  const float* gcnK_W   = (const float*)d_in[2];
  const float* gcnK_b   = (const float*)d_in[3];
  const float* gcnV_W   = (const float*)d_in[4];
  const float* gcnV_b   = (const float*)d_in[5];
  const float* super_Q  = (const float*)d_in[6];
  const float* mha_in_w = (const float*)d_in[7];
  const float* mha_in_b = (const float*)d_in[8];
  const float* mha_out_w= (const float*)d_in[9];
  const float* mha_out_b= (const float*)d_in[10];
  const float* gat_W    = (const float*)d_in[11];
  const float* gat_Wc   = (const float*)d_in[12];
  const float* gat_a_src= (const float*)d_in[13];
  const float* gat_a_dst= (const float*)d_in[14];
  const float* gat_b    = (const float*)d_in[15];
  const float* t1_W     = (const float*)d_in[16];
  const float* t1_b     = (const float*)d_in[17];
  const float* t2_W     = (const float*)d_in[18];
  const float* t2_b     = (const float*)d_in[19];

  char* ws = (char*)d_ws;
  size_t cur = 0;
  auto alloc = [&](size_t bytes) -> char* {
    char* p = ws + cur;
    cur = (cur + bytes + 255) & ~(size_t)255;
    return p;
  };
  // no zero-init needed: every buffer is fully written before first read
  int*      histmat = (int*)alloc((size_t)NBK * NCB * 4);
  int*      cbsum   = (int*)alloc((size_t)NCB * 4);
  int*      ppos    = (int*)alloc((size_t)NCB * NBK * 4);  // transposed [cb][blk]
  int*      bstart  = (int*)alloc((size_t)(NCB + 1) * 4);
  int*      offsets = (int*)alloc((size_t)(NN + 1) * 4);
  float*    dinv    = (float*)alloc((size_t)NN * 4);
  int*      csr     = (int*)alloc((size_t)EE * 4);
  unsigned* brec    = (unsigned*)alloc((size_t)EE * 4);
  float*    Wfk     = (float*)alloc(4096 * 4);
  float*    Wfv     = (float*)alloc(4096 * 4);
  float*    Wfg     = (float*)alloc(4096 * 4);
  float*    bfuse   = (float*)alloc(192 * 4);
  float*    qh      = (float*)alloc(640 * 4);
  float*    aeff    = (float*)alloc(64 * 4);
  float*    macc    = (float*)alloc(720 * 4);
  float*    part    = (float*)alloc((size_t)NPROJ * 720 * 4);  // per-proj-block MHA partials
  float*    part2   = (float*)alloc((size_t)NS * 720 * 4);     // stage-1 sums
  float*    s_src   = (float*)alloc((size_t)NN * 4);
  float*    s_dstv  = (float*)alloc((size_t)NN * 4);
  unsigned* xbf     = (unsigned*)alloc((size_t)NN * 128);   // bf16 x*dinv
  unsigned* axb     = (unsigned*)alloc((size_t)NN * 128);   // bf16 A_norm@x
  unsigned* hGb     = (unsigned*)alloc((size_t)NN * 128);   // bf16 GAT features
  unsigned* gb      = (unsigned*)alloc((size_t)NN * 128);   // bf16 GAT output
  unsigned* h1b     = (unsigned*)alloc((size_t)NN * 64 * 4); // bf16 MLP hidden (128/row)
  float*    g       = (float*)d_out;

  k_hist<<<NBK, 256, 0, stream>>>(ei, histmat);
  k_sumcb<<<NCB, 256, 0, stream>>>(histmat, cbsum);
  k_scancb<<<1, 128, 0, stream>>>(cbsum, bstart, offsets);
  k_ppos<<<NCB, 512, 0, stream>>>(histmat, bstart, ppos);
  k_fill_b<<<NBK, 256, 0, stream>>>(ei, ppos, brec);
  k_fill_c<<<NCB, 1024, 0, stream>>>(brec, bstart, csr, offsets, dinv);
  k_prep<<<(NN * 32 + 255) / 256, 256, 0, stream>>>(x, dinv, xbf);
  k_agg_x<<<NN / 4, 256, 0, stream>>>(xbf, offsets, csr, dinv, axb);
  k_fusew<<<52, 256, 0, stream>>>(gcnK_W, gcnK_b, gcnV_W, gcnV_b, mha_in_w, mha_in_b,
                                  gat_W, super_Q, Wfk, Wfv, Wfg, bfuse, qh);
  k_proj<<<NPROJ, 256, 0, stream>>>(axb, Wfk, Wfv, Wfg, bfuse, gat_a_dst, qh,
                                    hGb, s_dstv, part);
  k_mred1<<<NS, 256, 0, stream>>>(part, part2);
  k_mred2<<<3, 256, 0, stream>>>(part2, macc);
  k_context<<<1, 640, 0, stream>>>(macc, mha_out_w, mha_out_b, gat_a_src, gat_Wc, aeff);
  k_ssrc<<<NN / 4, 256, 0, stream>>>(hGb, aeff, s_src);
  k_gat<<<NN / 4, 256, 0, stream>>>(offsets, csr, s_src, s_dstv, hGb, gat_b, gb);
  k_mlp1<<<(NN + 31) / 32, 256, 0, stream>>>(gb, t1_W, t1_b, h1b);
  k_mlp2<<<(NN + 63) / 64, 256, 0, stream>>>(h1b, t2_W, t2_b, g);
}

// Round 18
// 440.143 us; speedup vs baseline: 1.0548x; 1.0191x over previous
//
#include <hip/hip_runtime.h>
#include <hip/hip_bf16.h>
#include <stdint.h>

#define NN 100000
#define EE 1600000
#define NBK 391        // fill blocks, 4096 edges each
#define CHUNK 4096
#define NCB 98         // coarse buckets of 1024 nodes (98*1024 >= NN)
#define NPROJ 1563     // (NN+63)/64 proj blocks
#define NS 32          // mred stage-1 splits

// fma of scalar xi with float4 vv into acc[base..base+3]
// (param name must NOT be 'x'/'y'/'z'/'w' — member tokens get macro-substituted!)
#define FMA4(xi, vv, a, base)                      \
  a[(base)+0] = fmaf((xi), (vv).x, a[(base)+0]);   \
  a[(base)+1] = fmaf((xi), (vv).y, a[(base)+1]);   \
  a[(base)+2] = fmaf((xi), (vv).z, a[(base)+2]);   \
  a[(base)+3] = fmaf((xi), (vv).w, a[(base)+3]);

__device__ inline unsigned pack_bf2(float a, float b) {
  __hip_bfloat162 t;
  t.x = __float2bfloat16(a);
  t.y = __float2bfloat16(b);
  return *reinterpret_cast<unsigned*>(&t);
}

// ---------------- per-block LDS histogram over 98 coarse buckets ----------------
__launch_bounds__(256)
__global__ void k_hist(const int* __restrict__ ei, int* __restrict__ histmat) {
  __shared__ int hist[NCB];
  int t = threadIdx.x;
  if (t < NCB) hist[t] = 0;
  __syncthreads();
  int base = blockIdx.x * CHUNK;
  int nb = EE - base; if (nb > CHUNK) nb = CHUNK;
  for (int k = t; k < nb; k += 256)
    atomicAdd(&hist[ei[EE + base + k] >> 10], 1);
  __syncthreads();
  if (t < NCB) histmat[blockIdx.x * NCB + t] = hist[t];
}

// ---------------- scan stage 1: column sums (98 blocks) ----------------
__launch_bounds__(256)
__global__ void k_sumcb(const int* __restrict__ histmat, int* __restrict__ cbsum) {
  __shared__ int red[4];
  int cb = blockIdx.x, t = threadIdx.x;
  int s = 0;
  for (int blk = t; blk < NBK; blk += 256) s += histmat[blk * NCB + cb];
#pragma unroll
  for (int off = 32; off > 0; off >>= 1) s += __shfl_down(s, off);
  if ((t & 63) == 0) red[t >> 6] = s;
  __syncthreads();
  if (t == 0) cbsum[cb] = red[0] + red[1] + red[2] + red[3];
}

// ---------------- scan stage 2+3 merged: bucket bases + per-bucket cursor scan ----
// Each of 98 blocks re-derives its own bstart from cbsum in-block (kills the
// separate k_scancb launch).
__launch_bounds__(512)
__global__ void k_ppos(const int* __restrict__ histmat, const int* __restrict__ cbsum,
                       int* __restrict__ bstart, int* __restrict__ offsets,
                       int* __restrict__ ppos) {
  __shared__ int sm[512];
  __shared__ int sb[128];
  int cb = blockIdx.x, t = threadIdx.x;
  if (t < 128) sb[t] = (t < NCB) ? cbsum[t] : 0;
  __syncthreads();
  for (int off = 1; off < 128; off <<= 1) {
    int x = (t < 128 && t >= off) ? sb[t - off] : 0;
    __syncthreads();
    if (t < 128) sb[t] += x;
    __syncthreads();
  }
  int bs = (cb == 0) ? 0 : sb[cb - 1];  // exclusive prefix (inclusive scan of prev)
  if (t == 0) bstart[cb] = bs;
  if (cb == 0 && t == 0) { bstart[NCB] = EE; offsets[NN] = EE; }
  int v = (t < NBK) ? histmat[t * NCB + cb] : 0;
  sm[t] = v;
  __syncthreads();
  for (int off = 1; off < 512; off <<= 1) {
    int x = (t >= off) ? sm[t - off] : 0;
    __syncthreads();
    sm[t] += x;
    __syncthreads();
  }
  if (t < NBK) ppos[cb * NBK + t] = bs + sm[t] - v;
}

// ---------------- fill pass B: LDS radix-partition + contiguous run copy ----------------
__launch_bounds__(256)
__global__ void k_fill_b(const int* __restrict__ ei, const int* __restrict__ ppos,
                         unsigned* __restrict__ brec) {
  __shared__ int hist[NCB], binstart[NCB], bincur[NCB], pbase[NCB];
  __shared__ unsigned lbuf[CHUNK];
  __shared__ unsigned char cbArr[CHUNK];
  int t = threadIdx.x;
  int base = blockIdx.x * CHUNK;
  int nb = EE - base; if (nb > CHUNK) nb = CHUNK;
  if (t < NCB) { hist[t] = 0; pbase[t] = ppos[t * NBK + blockIdx.x]; }
  __syncthreads();
  unsigned rec[16]; int rcb[16]; int cnt = 0;
  for (int k = t; k < nb; k += 256) {
    int s = ei[base + k], d = ei[EE + base + k];
    rec[cnt] = (unsigned)s | ((unsigned)(d & 1023) << 17);  // s < 2^17, dlocal 10b
    rcb[cnt] = d >> 10;
    atomicAdd(&hist[rcb[cnt]], 1);
    cnt++;
  }
  __syncthreads();
  if (t < NCB) binstart[t] = hist[t];
  __syncthreads();
  for (int off = 1; off < NCB; off <<= 1) {
    int v = (t < NCB && t >= off) ? binstart[t - off] : 0;
    __syncthreads();
    if (t < NCB) binstart[t] += v;
    __syncthreads();
  }
  if (t < NCB) { binstart[t] -= hist[t]; bincur[t] = 0; }
  __syncthreads();
  for (int i = 0; i < cnt; i++) {
    int c = rcb[i];
    int pos = atomicAdd(&bincur[c], 1);
    int p = binstart[c] + pos;
    lbuf[p] = rec[i];
    cbArr[p] = (unsigned char)c;
  }
  __syncthreads();
  for (int i = t; i < nb; i += 256) {
    int c = cbArr[i];
    brec[pbase[c] + (i - binstart[c])] = lbuf[i];
  }
}

// ---------------- fill pass C: bucket-local histogram + scan + place ----------------
__launch_bounds__(1024)
__global__ void k_fill_c(const unsigned* __restrict__ brec, const int* __restrict__ bstart,
                         int* __restrict__ csr, int* __restrict__ offsets,
                         float* __restrict__ dinv) {
  __shared__ int cnt[1024], sm[1024];
  int cbk = blockIdx.x, t = threadIdx.x;
  int nb0 = cbk << 10;
  int nn = NN - nb0; if (nn > 1024) nn = 1024;
  cnt[t] = 0;
  __syncthreads();
  int e0 = bstart[cbk], e1 = bstart[cbk + 1];
  for (int j = e0 + t; j < e1; j += 1024)
    atomicAdd(&cnt[brec[j] >> 17], 1);
  __syncthreads();
  int cv = cnt[t];
  sm[t] = cv;
  __syncthreads();
  for (int off = 1; off < 1024; off <<= 1) {
    int v = (t >= off) ? sm[t - off] : 0;
    __syncthreads();
    sm[t] += v;
    __syncthreads();
  }
  sm[t] -= cv;  // exclusive
  if (t < nn) {
    offsets[nb0 + t] = e0 + sm[t];
    dinv[nb0 + t] = rsqrtf((float)(cv + 1));  // deg includes self loop
  }
  cnt[t] = 0;  // reuse as placement cursor
  __syncthreads();
  for (int j = e0 + t; j < e1; j += 1024) {
    unsigned r = brec[j];
    int dl = r >> 17;
    int p = atomicAdd(&cnt[dl], 1);
    csr[e0 + sm[dl] + p] = r & 0x1FFFF;  // confined to this bucket's window
  }
}

// ---------------- x~ = bf16(x * dinv[row]) ----------------
__global__ void k_prep(const float* __restrict__ x, const float* __restrict__ dinv,
                       unsigned* __restrict__ xbf2) {
  int i = blockIdx.x * 256 + threadIdx.x;  // pair index
  if (i >= NN * 32) return;
  float dv = dinv[i >> 5];
  float2 v = ((const float2*)x)[i];
  xbf2[i] = pack_bf2(v.x * dv, v.y * dv);
}

// ---------------- ax = A_norm @ x (8-lane-group gather, 2x unrolled) ----------------
// 2x edge unroll: csr[j] and csr[j+8] loaded together -> 2 row-gathers in
// flight per lane-group (latency-bound loop; doubles MLP).
__launch_bounds__(256)
__global__ void k_agg_x(const unsigned* __restrict__ xbf2, const int* __restrict__ offsets,
                        const int* __restrict__ csr, const float* __restrict__ dinv,
                        unsigned* __restrict__ axb) {
  int gid = blockIdx.x * 256 + threadIdx.x;
  int n = gid >> 6;
  if (n >= NN) return;
  int lane = gid & 63, q = lane & 7, grp = lane >> 3;
  int e0 = offsets[n], e1 = offsets[n + 1];
  float dv = dinv[n];
  float a[8];
#pragma unroll
  for (int i = 0; i < 8; i++) a[i] = 0.f;
  if (grp == 0) {  // self loop, counted once
    uint4 u = ((const uint4*)(xbf2 + (size_t)n * 32))[q];
    unsigned uu[4] = {u.x, u.y, u.z, u.w};
#pragma unroll
    for (int p = 0; p < 4; p++) {
      __hip_bfloat162 v = *reinterpret_cast<__hip_bfloat162*>(&uu[p]);
      a[2 * p] += __bfloat162float(v.x);
      a[2 * p + 1] += __bfloat162float(v.y);
    }
  }
  int b2 = e0;
  for (; b2 + 8 < e1; b2 += 16) {
    int j0 = b2 + grp, j1 = j0 + 8;
    int s0 = csr[j0];
    bool ok1 = j1 < e1;
    int s1 = ok1 ? csr[j1] : s0;
    uint4 u0 = ((const uint4*)(xbf2 + (size_t)s0 * 32))[q];
    uint4 u1 = ((const uint4*)(xbf2 + (size_t)s1 * 32))[q];
    unsigned w0[4] = {u0.x, u0.y, u0.z, u0.w};
    unsigned w1[4] = {u1.x, u1.y, u1.z, u1.w};
#pragma unroll
    for (int p = 0; p < 4; p++) {
      __hip_bfloat162 v = *reinterpret_cast<__hip_bfloat162*>(&w0[p]);
      a[2 * p] += __bfloat162float(v.x);
      a[2 * p + 1] += __bfloat162float(v.y);
    }
    if (ok1) {
#pragma unroll
      for (int p = 0; p < 4; p++) {
        __hip_bfloat162 v = *reinterpret_cast<__hip_bfloat162*>(&w1[p]);
        a[2 * p] += __bfloat162float(v.x);
        a[2 * p + 1] += __bfloat162float(v.y);
      }
    }
  }
  for (; b2 < e1; b2 += 8) {
    int j = b2 + grp;
    if (j < e1) {
      int s = csr[j];
      uint4 u = ((const uint4*)(xbf2 + (size_t)s * 32))[q];
      unsigned uu[4] = {u.x, u.y, u.z, u.w};
#pragma unroll
      for (int p = 0; p < 4; p++) {
        __hip_bfloat162 v = *reinterpret_cast<__hip_bfloat162*>(&uu[p]);
        a[2 * p] += __bfloat162float(v.x);
        a[2 * p + 1] += __bfloat162float(v.y);
      }
    }
  }
#pragma unroll
  for (int i = 0; i < 8; i++) {
    a[i] += __shfl_xor(a[i], 8);
    a[i] += __shfl_xor(a[i], 16);
    a[i] += __shfl_xor(a[i], 32);
  }
  if (lane < 8) {
    uint4 u;
    u.x = pack_bf2(a[0] * dv, a[1] * dv);
    u.y = pack_bf2(a[2] * dv, a[3] * dv);
    u.z = pack_bf2(a[4] * dv, a[5] * dv);
    u.w = pack_bf2(a[6] * dv, a[7] * dv);
    ((uint4*)(axb + (size_t)n * 32))[q] = u;
  }
}

// ---------------- fused weights + qh (merged: blocks 49..51) ----------------
__global__ void k_fusew(const float* __restrict__ gcnK_W, const float* __restrict__ gcnK_b,
                        const float* __restrict__ gcnV_W, const float* __restrict__ gcnV_b,
                        const float* __restrict__ mha_in_w, const float* __restrict__ mha_in_b,
                        const float* __restrict__ gat_W, const float* __restrict__ sQ,
                        float* __restrict__ Wfk, float* __restrict__ Wfv,
                        float* __restrict__ Wfg, float* __restrict__ bf,
                        float* __restrict__ qh) {
  int blk = blockIdx.x;
  if (blk < 48) {
    int m = blk >> 4;
    int e = (blk & 15) * 256 + threadIdx.x;  // 0..4095
    int i = e >> 6, c = e & 63;
    float s = 0.f;
    if (m == 0) {
      for (int j = 0; j < 64; j++) s = fmaf(gcnK_W[i * 64 + j], mha_in_w[(64 + c) * 64 + j], s);
      Wfk[e] = s;
    } else if (m == 1) {
      for (int j = 0; j < 64; j++) s = fmaf(gcnV_W[i * 64 + j], mha_in_w[(128 + c) * 64 + j], s);
      Wfv[e] = s;
    } else {
      for (int j = 0; j < 64; j++) s = fmaf(gcnV_W[i * 64 + j], gat_W[j * 64 + c], s);
      Wfg[e] = s;
    }
  } else if (blk == 48) {
    int t = threadIdx.x;
    if (t < 64) {
      float s = mha_in_b[64 + t];
      for (int j = 0; j < 64; j++) s = fmaf(gcnK_b[j], mha_in_w[(64 + t) * 64 + j], s);
      bf[t] = s;
    } else if (t < 128) {
      int c = t - 64;
      float s = mha_in_b[128 + c];
      for (int j = 0; j < 64; j++) s = fmaf(gcnV_b[j], mha_in_w[(128 + c) * 64 + j], s);
      bf[64 + c] = s;
    } else if (t < 192) {
      int c = t - 128;
      float s = 0.f;
      for (int j = 0; j < 64; j++) s = fmaf(gcnV_b[j], gat_W[j * 64 + c], s);
      bf[128 + c] = s;
    }
  } else {
    int t = (blk - 49) * 256 + threadIdx.x;
    if (t < 640) {
      int l = t >> 6, c = t & 63;
      float acc = 0.f;
      for (int i = 0; i < 64; i++) acc = fmaf(sQ[l * 64 + i], mha_in_w[c * 64 + i], acc);
      qh[t] = (acc + mha_in_b[c]) * 0.35355339059327373f;  // 1/sqrt(8)
    }
  }
}

// ---------------- k_proj: axb -> hGb, s_dst + FUSED MHA partials ----------------
// Round-15 structure (best measured; rounds 14/16 falsified variants).
__launch_bounds__(256)
__global__ void k_proj(const unsigned* __restrict__ axb, const float* __restrict__ Wfk,
                       const float* __restrict__ Wfv, const float* __restrict__ Wfg,
                       const float* __restrict__ bf, const float* __restrict__ a_dst,
                       const float* __restrict__ qh,
                       unsigned* __restrict__ hGb, float* __restrict__ s_dstv,
                       float* __restrict__ part) {
  __shared__ float sX[64 * 65];  // +1 pad; reused as reduction scratch after FMA loop
  __shared__ float sWk[4096], sWv[4096], sWg[4096];
  __shared__ float sB[192], sAd[64], sq[640];
  int t = threadIdx.x;
  int base = blockIdx.x * 64;
  for (int i = t; i < 4096; i += 256) { sWk[i] = Wfk[i]; sWv[i] = Wfv[i]; sWg[i] = Wfg[i]; }
  if (t < 192) sB[t] = bf[t];
  if (t < 64) sAd[t] = a_dst[t];
  for (int i = t; i < 640; i += 256) sq[i] = qh[i];
  for (int idx = t; idx < 64 * 8; idx += 256) {
    int rl = idx >> 3, c8 = idx & 7;  // 8 bf16 per uint4 chunk
    int row = base + rl;
    uint4 u = (row < NN) ? ((const uint4*)(axb + (size_t)row * 32))[c8]
                         : make_uint4(0u, 0u, 0u, 0u);
    unsigned uu[4] = {u.x, u.y, u.z, u.w};
    float* dst = sX + rl * 65 + c8 * 8;
#pragma unroll
    for (int p = 0; p < 4; p++) {
      __hip_bfloat162 v = *reinterpret_cast<__hip_bfloat162*>(&uu[p]);
      dst[2 * p] = __bfloat162float(v.x);
      dst[2 * p + 1] = __bfloat162float(v.y);
    }
  }
  __syncthreads();
  int cg = t & 7, rg = t >> 3;  // rows 2rg, 2rg+1; cols 8cg..8cg+7 (= head cg)
  int r0 = rg * 2;
  float aK[16], aV[16], aG[16];
#pragma unroll
  for (int i = 0; i < 16; i++) { aK[i] = 0.f; aV[i] = 0.f; aG[i] = 0.f; }
  const float4* Wk4 = (const float4*)sWk;
  const float4* Wv4 = (const float4*)sWv;
  const float4* Wg4 = (const float4*)sWg;
#pragma unroll 2
  for (int i = 0; i < 64; i++) {
    float x0 = sX[r0 * 65 + i];
    float x1 = sX[(r0 + 1) * 65 + i];
    float4 wk0 = Wk4[i * 16 + cg * 2], wk1 = Wk4[i * 16 + cg * 2 + 1];
    float4 wv0 = Wv4[i * 16 + cg * 2], wv1 = Wv4[i * 16 + cg * 2 + 1];
    float4 wg0 = Wg4[i * 16 + cg * 2], wg1 = Wg4[i * 16 + cg * 2 + 1];
    FMA4(x0, wk0, aK, 0); FMA4(x0, wk1, aK, 4);
    FMA4(x1, wk0, aK, 8); FMA4(x1, wk1, aK, 12);
    FMA4(x0, wv0, aV, 0); FMA4(x0, wv1, aV, 4);
    FMA4(x1, wv0, aV, 8); FMA4(x1, wv1, aV, 12);
    FMA4(x0, wg0, aG, 0); FMA4(x0, wg1, aG, 4);
    FMA4(x1, wg0, aG, 8); FMA4(x1, wg1, aG, 12);
  }
  float s[10], o[80];
#pragma unroll
  for (int l = 0; l < 10; l++) s[l] = 0.f;
#pragma unroll
  for (int i = 0; i < 80; i++) o[i] = 0.f;
  const float4* sq4 = (const float4*)sq;
#pragma unroll
  for (int r = 0; r < 2; r++) {
    int row = base + r0 + r;
    bool ok = row < NN;
    int off = r * 8;
    float kv[8], vv[8], hg[8];
    float sd = 0.f;
#pragma unroll
    for (int c = 0; c < 8; c++) {
      kv[c] = aK[off + c] + sB[cg * 8 + c];
      vv[c] = aV[off + c] + sB[64 + cg * 8 + c];
      hg[c] = aG[off + c] + sB[128 + cg * 8 + c];
      sd = fmaf(hg[c], sAd[cg * 8 + c], sd);
    }
    sd += __shfl_xor(sd, 1);
    sd += __shfl_xor(sd, 2);
    sd += __shfl_xor(sd, 4);
    if (ok) {
      // fused MHA accumulation (q slice for head cg from LDS)
#pragma unroll
      for (int l = 0; l < 10; l++) {
        float4 q0 = sq4[l * 16 + cg * 2], q1 = sq4[l * 16 + cg * 2 + 1];
        float z = q0.x * kv[0] + q0.y * kv[1] + q0.z * kv[2] + q0.w * kv[3] +
                  q1.x * kv[4] + q1.y * kv[5] + q1.z * kv[6] + q1.w * kv[7];
        float w = __expf(z);
        s[l] += w;
#pragma unroll
        for (int c = 0; c < 8; c++) o[l * 8 + c] = fmaf(w, vv[c], o[l * 8 + c]);
      }
      uint4 u;
      u.x = pack_bf2(hg[0], hg[1]);
      u.y = pack_bf2(hg[2], hg[3]);
      u.z = pack_bf2(hg[4], hg[5]);
      u.w = pack_bf2(hg[6], hg[7]);
      ((uint4*)(hGb + (size_t)row * 32))[cg] = u;
      if (cg == 0) s_dstv[row] = sd;
    }
  }
  // reduce s/o across the 32 same-head threads per wave (lanes stride 8)
#pragma unroll
  for (int l = 0; l < 10; l++) {
    s[l] += __shfl_xor(s[l], 8);
    s[l] += __shfl_xor(s[l], 16);
    s[l] += __shfl_xor(s[l], 32);
  }
#pragma unroll
  for (int i = 0; i < 80; i++) {
    o[i] += __shfl_xor(o[i], 8);
    o[i] += __shfl_xor(o[i], 16);
    o[i] += __shfl_xor(o[i], 32);
  }
  __syncthreads();  // sX reads done everywhere; safe to reuse as scratch
  float* scratch = sX;  // need 4*720 = 2880 floats <= 4160
  int lane = t & 63, wave = t >> 6;
  if (lane < 8) {
#pragma unroll
    for (int l = 0; l < 10; l++) scratch[wave * 720 + lane * 90 + l] = s[l];
#pragma unroll
    for (int i = 0; i < 80; i++) scratch[wave * 720 + lane * 90 + 10 + i] = o[i];
  }
  __syncthreads();
  for (int j = t; j < 720; j += 256) {
    float v = scratch[j] + scratch[720 + j] + scratch[1440 + j] + scratch[2160 + j];
    part[(size_t)blockIdx.x * 720 + j] = v;  // coalesced per block
  }
}

// ---------------- mred stage 1: 32 splits x 720 cols (coalesced) ----------------
__launch_bounds__(256)
__global__ void k_mred1(const float* __restrict__ part, float* __restrict__ part2) {
  int blk = blockIdx.x, t = threadIdx.x;
  int per = (NPROJ + NS - 1) / NS;  // 49
  int b0 = blk * per, b1 = b0 + per; if (b1 > NPROJ) b1 = NPROJ;
  float v0 = 0.f, v1 = 0.f, v2 = 0.f;
  for (int b = b0; b < b1; b++) {
    const float* row = part + (size_t)b * 720;
    v0 += row[t];
    if (t + 256 < 720) v1 += row[t + 256];
    if (t + 512 < 720) v2 += row[t + 512];
  }
  part2[(size_t)blk * 720 + t] = v0;
  if (t + 256 < 720) part2[(size_t)blk * 720 + t + 256] = v1;
  if (t + 512 < 720) part2[(size_t)blk * 720 + t + 512] = v2;
}

// ---------------- context (merged mred2): fold 32 splits -> softmax -> a_eff ----
__global__ void k_context(const float* __restrict__ part2, const float* __restrict__ out_w,
                          const float* __restrict__ out_b, const float* __restrict__ a_src,
                          const float* __restrict__ gat_Wc, float* __restrict__ aeff) {
  __shared__ float po[640], cl[640], ctx[64], ac[720];
  int t = threadIdx.x;  // blockDim = 640
  for (int j = t; j < 720; j += 640) {
    float v = 0.f;
#pragma unroll
    for (int s = 0; s < NS; s++) v += part2[(size_t)s * 720 + j];
    int cg = j / 90, r = j % 90;
    ac[(r < 10) ? (cg * 10 + r) : (80 + cg * 80 + (r - 10))] = v;
  }
  __syncthreads();
  {
    int h = t / 80, r = t % 80, l = r >> 3, j = r & 7;
    po[l * 64 + h * 8 + j] = ac[80 + t] / ac[h * 10 + l];
  }
  __syncthreads();
  {
    int l = t >> 6, d = t & 63;
    float v = out_b[d];
    for (int c = 0; c < 64; c++) v = fmaf(po[l * 64 + c], out_w[d * 64 + c], v);
    cl[t] = v;
  }
  __syncthreads();
  if (t < 64) {
    float m = 0.f;
#pragma unroll
    for (int l = 0; l < 10; l++) m += cl[l * 64 + t];
    ctx[t] = m * 0.1f;
  }
  __syncthreads();
  if (t < 64) {
    float v = a_src[t];
    for (int i = 0; i < 64; i++) v = fmaf(ctx[i], gat_Wc[i * 64 + t], v);
    aeff[t] = v;
  }
}

// ---------------- s_src[n] = dot(hG[n], a_eff) ----------------
__launch_bounds__(256)
__global__ void k_ssrc(const unsigned* __restrict__ hGb, const float* __restrict__ aeff,
                       float* __restrict__ s_src) {
  int gid = blockIdx.x * 256 + threadIdx.x;
  int n = gid >> 6, lane = gid & 63;
  if (n >= NN) return;
  const __hip_bfloat16* hp = (const __hip_bfloat16*)hGb;
  float v = __bfloat162float(hp[(size_t)n * 64 + lane]) * aeff[lane];
#pragma unroll
  for (int off = 32; off > 0; off >>= 1) v += __shfl_xor(v, off);
  if (lane == 0) s_src[n] = v;
}

// ---------------- GAT: 8-lane-group gather (2x unrolled) -> bf16 output ----------------
__launch_bounds__(256)
__global__ void k_gat(const int* __restrict__ offsets, const int* __restrict__ csr,
                      const float* __restrict__ s_src, const float* __restrict__ s_dstv,
                      const unsigned* __restrict__ hGb, const float* __restrict__ gat_b,
                      unsigned* __restrict__ gb) {
  int gid = blockIdx.x * 256 + threadIdx.x;
  int n = gid >> 6;
  if (n >= NN) return;
  int lane = gid & 63, q = lane & 7, grp = lane >> 3;
  int e0 = offsets[n], e1 = offsets[n + 1];
  float sd = s_dstv[n];
  float den = 0.f;
  float a[8];
#pragma unroll
  for (int i = 0; i < 8; i++) a[i] = 0.f;
  int b2 = e0;
  for (; b2 + 8 < e1; b2 += 16) {
    int j0 = b2 + grp, j1 = j0 + 8;
    int s0 = csr[j0];
    bool ok1 = j1 < e1;
    int s1 = ok1 ? csr[j1] : s0;
    float z0 = s_src[s0] + sd;
    float z1 = s_src[s1] + sd;
    uint4 u0 = ((const uint4*)(hGb + (size_t)s0 * 32))[q];
    uint4 u1 = ((const uint4*)(hGb + (size_t)s1 * 32))[q];
    unsigned w0[4] = {u0.x, u0.y, u0.z, u0.w};
    unsigned w1[4] = {u1.x, u1.y, u1.z, u1.w};
    z0 = z0 > 0.f ? z0 : 0.2f * z0;
    float ex0 = __expf(z0);  // logits O(1): softmax shift-invariant, skip segment-max
    den += ex0;
#pragma unroll
    for (int p = 0; p < 4; p++) {
      __hip_bfloat162 v = *reinterpret_cast<__hip_bfloat162*>(&w0[p]);
      a[2 * p] = fmaf(ex0, __bfloat162float(v.x), a[2 * p]);
      a[2 * p + 1] = fmaf(ex0, __bfloat162float(v.y), a[2 * p + 1]);
    }
    if (ok1) {
      z1 = z1 > 0.f ? z1 : 0.2f * z1;
      float ex1 = __expf(z1);
      den += ex1;
#pragma unroll
      for (int p = 0; p < 4; p++) {
        __hip_bfloat162 v = *reinterpret_cast<__hip_bfloat162*>(&w1[p]);
        a[2 * p] = fmaf(ex1, __bfloat162float(v.x), a[2 * p]);
        a[2 * p + 1] = fmaf(ex1, __bfloat162float(v.y), a[2 * p + 1]);
      }
    }
  }
  for (; b2 < e1; b2 += 8) {
    int j = b2 + grp;
    if (j < e1) {
      int s = csr[j];
      float z = s_src[s] + sd;
      z = z > 0.f ? z : 0.2f * z;
      float ex = __expf(z);
      den += ex;
      uint4 u = ((const uint4*)(hGb + (size_t)s * 32))[q];
      unsigned uu[4] = {u.x, u.y, u.z, u.w};
#pragma unroll
      for (int p = 0; p < 4; p++) {
        __hip_bfloat162 v = *reinterpret_cast<__hip_bfloat162*>(&uu[p]);
        a[2 * p] = fmaf(ex, __bfloat162float(v.x), a[2 * p]);
        a[2 * p + 1] = fmaf(ex, __bfloat162float(v.y), a[2 * p + 1]);
      }
    }
  }
  den += __shfl_xor(den, 8);
  den += __shfl_xor(den, 16);
  den += __shfl_xor(den, 32);
#pragma unroll
  for (int i = 0; i < 8; i++) {
    a[i] += __shfl_xor(a[i], 8);
    a[i] += __shfl_xor(a[i], 16);
    a[i] += __shfl_xor(a[i], 32);
  }
  float inv = 1.f / (den + 1e-16f);
  if (lane < 8) {
    uint4 u;
    u.x = pack_bf2(a[0] * inv + gat_b[q * 8 + 0], a[1] * inv + gat_b[q * 8 + 1]);
    u.y = pack_bf2(a[2] * inv + gat_b[q * 8 + 2], a[3] * inv + gat_b[q * 8 + 3]);
    u.z = pack_bf2(a[4] * inv + gat_b[q * 8 + 4], a[5] * inv + gat_b[q * 8 + 5]);
    u.w = pack_bf2(a[6] * inv + gat_b[q * 8 + 6], a[7] * inv + gat_b[q * 8 + 7]);
    ((uint4*)(gb + (size_t)n * 32))[q] = u;
  }
}

// ---------------- MLP stage 1: h1 = relu(g@W1+b1) -> bf16 (2r x 8c / thread) ----------------
__launch_bounds__(256)
__global__ void k_mlp1(const unsigned* __restrict__ gb, const float* __restrict__ W1,
                       const float* __restrict__ b1, unsigned* __restrict__ h1b) {
  __shared__ float sX[32 * 65];
  __shared__ float sW[64 * 128];
  __shared__ float sb[128];
  int t = threadIdx.x;
  int base = blockIdx.x * 32;
  for (int i = t; i < 8192; i += 256) sW[i] = W1[i];
  if (t < 128) sb[t] = b1[t];
  for (int idx = t; idx < 32 * 8; idx += 256) {
    int rl = idx >> 3, c8 = idx & 7;
    int row = base + rl;
    uint4 u = (row < NN) ? ((const uint4*)(gb + (size_t)row * 32))[c8]
                         : make_uint4(0u, 0u, 0u, 0u);
    unsigned uu[4] = {u.x, u.y, u.z, u.w};
    float* dst = sX + rl * 65 + c8 * 8;
#pragma unroll
    for (int p = 0; p < 4; p++) {
      __hip_bfloat162 v = *reinterpret_cast<__hip_bfloat162*>(&uu[p]);
      dst[2 * p] = __bfloat162float(v.x);
      dst[2 * p + 1] = __bfloat162float(v.y);
    }
  }
  __syncthreads();
  int cg = t & 15, rg = t >> 4;  // rows 2rg, 2rg+1; cols 8cg..8cg+7
  int r0 = rg * 2;
  float a0[8], a1[8];
#pragma unroll
  for (int i = 0; i < 8; i++) { a0[i] = 0.f; a1[i] = 0.f; }
  const float4* W4 = (const float4*)sW;
#pragma unroll 4
  for (int i = 0; i < 64; i++) {
    float x0 = sX[r0 * 65 + i];
    float x1 = sX[(r0 + 1) * 65 + i];
    float4 w0 = W4[i * 32 + cg * 2], w1 = W4[i * 32 + cg * 2 + 1];
    FMA4(x0, w0, a0, 0); FMA4(x0, w1, a0, 4);
    FMA4(x1, w0, a1, 0); FMA4(x1, w1, a1, 4);
  }
#pragma unroll
  for (int r = 0; r < 2; r++) {
    int row = base + r0 + r;
    if (row >= NN) continue;
    float* a = r ? a1 : a0;
    float h[8];
#pragma unroll
    for (int c = 0; c < 8; c++) h[c] = fmaxf(a[c] + sb[cg * 8 + c], 0.f);
    uint4 u;
    u.x = pack_bf2(h[0], h[1]);
    u.y = pack_bf2(h[2], h[3]);
    u.z = pack_bf2(h[4], h[5]);
    u.w = pack_bf2(h[6], h[7]);
    ((uint4*)(h1b + (size_t)row * 64))[cg] = u;
  }
}

// ---------------- MLP stage 2: out = relu(h1@W2+b2) (2r x 8c / thread) ----------------
__launch_bounds__(256)
__global__ void k_mlp2(const unsigned* __restrict__ h1b, const float* __restrict__ W2,
                       const float* __restrict__ b2, float* __restrict__ out) {
  __shared__ unsigned sH[64 * 65];  // bf16 pairs
  __shared__ float sW[128 * 64];
  __shared__ float sb[64];
  int t = threadIdx.x;
  int base = blockIdx.x * 64;
  for (int i = t; i < 8192; i += 256) sW[i] = W2[i];
  if (t < 64) sb[t] = b2[t];
  for (int idx = t; idx < 64 * 16; idx += 256) {
    int rl = idx >> 4, c4 = idx & 15;
    int row = base + rl;
    uint4 v = (row < NN) ? ((const uint4*)h1b)[(size_t)row * 16 + c4]
                         : make_uint4(0u, 0u, 0u, 0u);
    sH[rl * 65 + 4 * c4 + 0] = v.x;
    sH[rl * 65 + 4 * c4 + 1] = v.y;
    sH[rl * 65 + 4 * c4 + 2] = v.z;
    sH[rl * 65 + 4 * c4 + 3] = v.w;
  }
  __syncthreads();
  int cg = t & 7, rg = t >> 3;  // rows 2rg, 2rg+1; cols 8cg..8cg+7
  int r0 = rg * 2;
  float a0[8], a1[8];
#pragma unroll
  for (int i = 0; i < 8; i++) { a0[i] = 0.f; a1[i] = 0.f; }
  const float4* W4 = (const float4*)sW;
#pragma unroll 2
  for (int kp = 0; kp < 64; kp++) {
    unsigned u0 = sH[r0 * 65 + kp];
    unsigned u1 = sH[(r0 + 1) * 65 + kp];
    float x0a = __uint_as_float(u0 << 16), x0b = __uint_as_float(u0 & 0xffff0000u);
    float x1a = __uint_as_float(u1 << 16), x1b = __uint_as_float(u1 & 0xffff0000u);
    int k0 = 2 * kp, k1 = 2 * kp + 1;
    float4 wa0 = W4[k0 * 16 + cg * 2], wa1 = W4[k0 * 16 + cg * 2 + 1];
    float4 wb0 = W4[k1 * 16 + cg * 2], wb1 = W4[k1 * 16 + cg * 2 + 1];
    FMA4(x0a, wa0, a0, 0); FMA4(x0a, wa1, a0, 4);
    FMA4(x0b, wb0, a0, 0); FMA4(x0b, wb1, a0, 4);
    FMA4(x1a, wa0, a1, 0); FMA4(x1a, wa1, a1, 4);
    FMA4(x1b, wb0, a1, 0); FMA4(x1b, wb1, a1, 4);
  }
#pragma unroll
  for (int r = 0; r < 2; r++) {
    int row = base + r0 + r;
    if (row >= NN) continue;
    float* a = r ? a1 : a0;
    float4* op = (float4*)(out + (size_t)row * 64 + cg * 8);
    op[0] = make_float4(fmaxf(a[0] + sb[cg * 8 + 0], 0.f), fmaxf(a[1] + sb[cg * 8 + 1], 0.f),
                        fmaxf(a[2] + sb[cg * 8 + 2], 0.f), fmaxf(a[3] + sb[cg * 8 + 3], 0.f));
    op[1] = make_float4(fmaxf(a[4] + sb[cg * 8 + 4], 0.f), fmaxf(a[5] + sb[cg * 8 + 5], 0.f),
                        fmaxf(a[6] + sb[cg * 8 + 6], 0.f), fmaxf(a[7] + sb[cg * 8 + 7], 0.f));
  }
}

// ---------------- host ----------------
extern "C" void kernel_launch(void* const* d_in, const int* in_sizes, int n_in,
                              void* d_out, int out_size, void* d_ws, size_t ws_size,
                              hipStream_t stream) {
  (void)in_sizes; (void)n_in; (void)out_size; (void)ws_size;
  const float* x        = (const float*)d_in[0];
  const int*   ei       = (const int*)d_in[1];
  const float* gcnK_W   = (const float*)d_in[2];
  const float* gcnK_b   = (const float*)d_in[3];
  const float* gcnV_W   = (const float*)d_in[4];
  const float* gcnV_b   = (const float*)d_in[5];
  const float* super_Q  = (const float*)d_in[6];
  const float* mha_in_w = (const float*)d_in[7];
  const float* mha_in_b = (const float*)d_in[8];
  const float* mha_out_w= (const float*)d_in[9];
  const float* mha_out_b= (const float*)d_in[10];
  const float* gat_W    = (const float*)d_in[11];
  const float* gat_Wc   = (const float*)d_in[12];
  const float* gat_a_src= (const float*)d_in[13];
  const float* gat_a_dst= (const float*)d_in[14];
  const float* gat_b    = (const float*)d_in[15];
  const float* t1_W     = (const float*)d_in[16];
  const float* t1_b     = (const float*)d_in[17];
  const float* t2_W     = (const float*)d_in[18];
  const float* t2_b     = (const float*)d_in[19];

  char* ws = (char*)d_ws;
  size_t cur = 0;
  auto alloc = [&](size_t bytes) -> char* {
    char* p = ws + cur;
    cur = (cur + bytes + 255) & ~(size_t)255;
    return p;
  };
  // no zero-init needed: every buffer is fully written before first read
  int*      histmat = (int*)alloc((size_t)NBK * NCB * 4);
  int*      cbsum   = (int*)alloc((size_t)NCB * 4);
  int*      ppos    = (int*)alloc((size_t)NCB * NBK * 4);  // transposed [cb][blk]
  int*      bstart  = (int*)alloc((size_t)(NCB + 1) * 4);
  int*      offsets = (int*)alloc((size_t)(NN + 1) * 4);
  float*    dinv    = (float*)alloc((size_t)NN * 4);
  int*      csr     = (int*)alloc((size_t)EE * 4);
  unsigned* brec    = (unsigned*)alloc((size_t)EE * 4);
  float*    Wfk     = (float*)alloc(4096 * 4);
  float*    Wfv     = (float*)alloc(4096 * 4);
  float*    Wfg     = (float*)alloc(4096 * 4);
  float*    bfuse   = (float*)alloc(192 * 4);
  float*    qh      = (float*)alloc(640 * 4);
  float*    aeff    = (float*)alloc(64 * 4);
  float*    part    = (float*)alloc((size_t)NPROJ * 720 * 4);  // per-proj-block MHA partials
  float*    part2   = (float*)alloc((size_t)NS * 720 * 4);     // stage-1 sums
  float*    s_src   = (float*)alloc((size_t)NN * 4);
  float*    s_dstv  = (float*)alloc((size_t)NN * 4);
  unsigned* xbf     = (unsigned*)alloc((size_t)NN * 128);   // bf16 x*dinv
  unsigned* axb     = (unsigned*)alloc((size_t)NN * 128);   // bf16 A_norm@x
  unsigned* hGb     = (unsigned*)alloc((size_t)NN * 128);   // bf16 GAT features
  unsigned* gb      = (unsigned*)alloc((size_t)NN * 128);   // bf16 GAT output
  unsigned* h1b     = (unsigned*)alloc((size_t)NN * 64 * 4); // bf16 MLP hidden (128/row)
  float*    g       = (float*)d_out;

  k_hist<<<NBK, 256, 0, stream>>>(ei, histmat);
  k_sumcb<<<NCB, 256, 0, stream>>>(histmat, cbsum);
  k_ppos<<<NCB, 512, 0, stream>>>(histmat, cbsum, bstart, offsets, ppos);
  k_fill_b<<<NBK, 256, 0, stream>>>(ei, ppos, brec);
  k_fill_c<<<NCB, 1024, 0, stream>>>(brec, bstart, csr, offsets, dinv);
  k_prep<<<(NN * 32 + 255) / 256, 256, 0, stream>>>(x, dinv, xbf);
  k_agg_x<<<NN / 4, 256, 0, stream>>>(xbf, offsets, csr, dinv, axb);
  k_fusew<<<52, 256, 0, stream>>>(gcnK_W, gcnK_b, gcnV_W, gcnV_b, mha_in_w, mha_in_b,
                                  gat_W, super_Q, Wfk, Wfv, Wfg, bfuse, qh);
  k_proj<<<NPROJ, 256, 0, stream>>>(axb, Wfk, Wfv, Wfg, bfuse, gat_a_dst, qh,
                                    hGb, s_dstv, part);
  k_mred1<<<NS, 256, 0, stream>>>(part, part2);
  k_context<<<1, 640, 0, stream>>>(part2, mha_out_w, mha_out_b, gat_a_src, gat_Wc, aeff);
  k_ssrc<<<NN / 4, 256, 0, stream>>>(hGb, aeff, s_src);
  k_gat<<<NN / 4, 256, 0, stream>>>(offsets, csr, s_src, s_dstv, hGb, gat_b, gb);
  k_mlp1<<<(NN + 31) / 32, 256, 0, stream>>>(gb, t1_W, t1_b, h1b);
  k_mlp2<<<(NN + 63) / 64, 256, 0, stream>>>(h1b, t2_W, t2_b, g);
}